// Round 1
// baseline (399.484 us; speedup 1.0000x reference)
//
#include <hip/hip_runtime.h>

typedef unsigned short u16;
typedef unsigned int   u32;
typedef __bf16  bf16x8 __attribute__((ext_vector_type(8)));
typedef float   f32x4  __attribute__((ext_vector_type(4)));

#define SEQ    2048
#define HEADS  16
#define DM     1024
#define NBH    32      /* B*H */
#define NBS    4096    /* B*S */

__device__ __forceinline__ u16 f2b(float f) {
    u32 x;
    __builtin_memcpy(&x, &f, 4);
    return (u16)((x + 0x7fffu + ((x >> 16) & 1u)) >> 16);  // RNE
}

__device__ __forceinline__ u32 pk2(float lo, float hi) {
    return (u32)f2b(lo) | ((u32)f2b(hi) << 16);
}

__device__ __forceinline__ bf16x8 ld_bf8(const u16* p) {
    return *(const bf16x8*)p;
}
__device__ __forceinline__ bf16x8 ld_f32x8_cvt(const float* p) {
    f32x4 a = *(const f32x4*)p;
    f32x4 b = *(const f32x4*)(p + 4);
    bf16x8 r;
    r[0] = (__bf16)a[0]; r[1] = (__bf16)a[1]; r[2] = (__bf16)a[2]; r[3] = (__bf16)a[3];
    r[4] = (__bf16)b[0]; r[5] = (__bf16)b[1]; r[6] = (__bf16)b[2]; r[7] = (__bf16)b[3];
    return r;
}

// ---------------------------------------------------------------------------
// Transpose + fp32->bf16 of W_Q/W_K/W_V: (k,n) -> WqkvT[z*1024 + n][k].
// ---------------------------------------------------------------------------
__global__ __launch_bounds__(256) void transpose_wqkv(const float* __restrict__ Wq,
                                                      const float* __restrict__ Wk,
                                                      const float* __restrict__ Wv,
                                                      u16* __restrict__ WqkvT) {
    __shared__ u16 tile[64][65];
    const int z  = blockIdx.z;
    const float* src = (z == 0) ? Wq : (z == 1) ? Wk : Wv;
    const int k0 = blockIdx.x * 64, n0 = blockIdx.y * 64;
    const int tid = threadIdx.x;
    for (int i = 0; i < 16; ++i) {
        int e = i * 256 + tid;
        int r = e >> 6, c = e & 63;
        tile[r][c] = f2b(src[(size_t)(k0 + r) * DM + n0 + c]);
    }
    __syncthreads();
    u16* dst = WqkvT + (size_t)z * DM * DM;
    for (int i = 0; i < 16; ++i) {
        int e = i * 256 + tid;
        int r = e >> 6, c = e & 63;
        dst[(size_t)(n0 + r) * DM + k0 + c] = tile[c][r];
    }
}

// W_O (k,n) fp32 -> WoT[n][k] bf16. Launched AFTER flash (overlays dead vt).
__global__ __launch_bounds__(256) void transpose_wo(const float* __restrict__ Wo,
                                                    u16* __restrict__ WoT) {
    __shared__ u16 tile[64][65];
    const int k0 = blockIdx.x * 64, n0 = blockIdx.y * 64;
    const int tid = threadIdx.x;
    for (int i = 0; i < 16; ++i) {
        int e = i * 256 + tid;
        int r = e >> 6, c = e & 63;
        tile[r][c] = f2b(Wo[(size_t)(k0 + r) * DM + n0 + c]);
    }
    __syncthreads();
    for (int i = 0; i < 16; ++i) {
        int e = i * 256 + tid;
        int r = e >> 6, c = e & 63;
        WoT[(size_t)(n0 + r) * DM + k0 + c] = tile[c][r];
    }
}

// ---------------------------------------------------------------------------
// Shared GEMM body: 128x128 tile, BK=64, VGPR-mediated staging,
// 4 waves 2x2, 4x4 16x16x32 MFMA tiles per wave. acc[][] left for epilogue.
// ---------------------------------------------------------------------------
#define GEMM_BODY(A_EXPR, B_EXPR, K)                                                \
    __shared__ __attribute__((aligned(16))) __bf16 As[128 * 64];                    \
    __shared__ __attribute__((aligned(16))) __bf16 Bs[128 * 64];                    \
    const int tid  = threadIdx.x;                                                   \
    const int wave = tid >> 6, lane = tid & 63;                                     \
    const int quad = lane >> 4, col = lane & 15;                                    \
    const int wm = wave >> 1, wn = wave & 1;                                        \
    const int m0 = blockIdx.x * 128, n0 = blockIdx.y * 128;                         \
    const int srow = tid >> 3;            /* 0..31 */                               \
    const int scol = (tid & 7) * 8;       /* 0..56 */                               \
    f32x4 zero = {0.f, 0.f, 0.f, 0.f};                                              \
    f32x4 acc[4][4];                                                                \
    for (int i = 0; i < 4; ++i)                                                     \
        for (int j = 0; j < 4; ++j) acc[i][j] = zero;                               \
    for (int k0 = 0; k0 < (K); k0 += 64) {                                          \
        bf16x8 av[4], bv[4];                                                        \
        for (int p = 0; p < 4; ++p) {                                               \
            int row = p * 32 + srow;                                                \
            av[p] = A_EXPR;                                                         \
            bv[p] = B_EXPR;                                                         \
        }                                                                           \
        __syncthreads();                                                            \
        for (int p = 0; p < 4; ++p) {                                               \
            int row = p * 32 + srow;                                                \
            *(bf16x8*)&As[row * 64 + scol] = av[p];                                 \
            *(bf16x8*)&Bs[row * 64 + scol] = bv[p];                                 \
        }                                                                           \
        __syncthreads();                                                            \
        for (int ks = 0; ks < 2; ++ks) {                                            \
            bf16x8 af[4], bfr[4];                                                   \
            for (int mt = 0; mt < 4; ++mt)                                          \
                af[mt] = *(const bf16x8*)&As[(wm * 64 + mt * 16 + col) * 64 +       \
                                             ks * 32 + quad * 8];                   \
            for (int nt = 0; nt < 4; ++nt)                                          \
                bfr[nt] = *(const bf16x8*)&Bs[(wn * 64 + nt * 16 + col) * 64 +      \
                                              ks * 32 + quad * 8];                  \
            for (int mt = 0; mt < 4; ++mt)                                          \
                for (int nt = 0; nt < 4; ++nt)                                      \
                    acc[mt][nt] = __builtin_amdgcn_mfma_f32_16x16x32_bf16(          \
                        af[mt], bfr[nt], acc[mt][nt], 0, 0, 0);                     \
        }                                                                           \
    }

// ---------------------------------------------------------------------------
// Fused QKV GEMM: x(4096x1024 fp32) x WqkvT(3072x1024 bf16)^T.
// Epilogue scatters to Qp (bh,s,d), Kp (bh,s,d), Vt (bh,d,s).
// ---------------------------------------------------------------------------
__global__ __launch_bounds__(256) void gemm_qkv(const float* __restrict__ Af,
                                                const u16* __restrict__ Bt,
                                                u16* __restrict__ Qp,
                                                u16* __restrict__ Kp,
                                                u16* __restrict__ Vt) {
    GEMM_BODY(ld_f32x8_cvt(Af + (size_t)(m0 + row) * DM + k0 + scol),
              ld_bf8(Bt + (size_t)(n0 + row) * DM + k0 + scol), DM)
    // C/D: col = lane&15, row = quad*4 + reg (m89-verified).
    for (int mt = 0; mt < 4; ++mt)
        for (int nt = 0; nt < 4; ++nt) {
            int cc = n0 + wn * 64 + nt * 16 + col;       // [0,3072)
            int which = cc >> 10;                        // 0=Q 1=K 2=V
            int c1 = cc & 1023;
            int h = c1 >> 6, d = c1 & 63;
            for (int r = 0; r < 4; ++r) {
                int row = m0 + wm * 64 + mt * 16 + quad * 4 + r;   // [0,4096)
                int b = row >> 11, s = row & (SEQ - 1);
                u16 val = f2b(acc[mt][nt][r]);
                size_t bh = (size_t)(b * HEADS + h);
                if (which == 0)
                    Qp[(bh * SEQ + s) * 64 + d] = val;
                else if (which == 1)
                    Kp[(bh * SEQ + s) * 64 + d] = val;
                else
                    Vt[(bh * 64 + d) * SEQ + s] = val;
            }
        }
}

// ---------------------------------------------------------------------------
// Output GEMM: ao(4096x1024 bf16) x WoT(1024x1024 bf16)^T -> out FP32.
// ---------------------------------------------------------------------------
__global__ __launch_bounds__(256) void gemm_wo(const u16* __restrict__ A,
                                               const u16* __restrict__ Bt,
                                               float* __restrict__ C) {
    GEMM_BODY(ld_bf8(A + (size_t)(m0 + row) * DM + k0 + scol),
              ld_bf8(Bt + (size_t)(n0 + row) * DM + k0 + scol), DM)
    for (int mt = 0; mt < 4; ++mt)
        for (int nt = 0; nt < 4; ++nt)
            for (int r = 0; r < 4; ++r) {
                int row = m0 + wm * 64 + mt * 16 + quad * 4 + r;
                int cc  = n0 + wn * 64 + nt * 16 + col;
                C[(size_t)row * DM + cc] = acc[mt][nt][r];
            }
}

// ---------------------------------------------------------------------------
// RoPE for Q,K in-place on (bh,s,d) bf16; cos/sin fp32 (S x 32).
// token_positions == arange(SEQ). 8192 blocks x 256.
// NOTE: folds the attention scale 1/sqrt(dk)=0.125 into Q (rotation commutes
// with scaling), so flash_attn needs no per-score multiply.
// ---------------------------------------------------------------------------
__global__ __launch_bounds__(256) void rope_qk(u16* __restrict__ Qp,
                                               u16* __restrict__ Kp,
                                               const float* __restrict__ cosT,
                                               const float* __restrict__ sinT) {
    int t = blockIdx.x * 256 + threadIdx.x;         // [0, 2^21)
    int p  = t & 31;
    int s  = (t >> 5) & (SEQ - 1);
    int hh = (t >> 16) & (HEADS - 1);
    int b  = t >> 20;

    float cv = cosT[s * 32 + p];
    float sv = sinT[s * 32 + p];

    size_t addr = (((size_t)(b * HEADS + hh)) * SEQ + s) * 64 + 2 * p;
    u32 q2 = *(const u32*)(Qp + addr);
    u32 k2 = *(const u32*)(Kp + addr);
    u32 qe_b = (q2 & 0xffff) << 16, qo_b = q2 & 0xffff0000u;
    u32 ke_b = (k2 & 0xffff) << 16, ko_b = k2 & 0xffff0000u;
    float qe, qo, ke, ko;
    __builtin_memcpy(&qe, &qe_b, 4); __builtin_memcpy(&qo, &qo_b, 4);
    __builtin_memcpy(&ke, &ke_b, 4); __builtin_memcpy(&ko, &ko_b, 4);

    u32 qout = (u32)f2b(0.125f * (cv * qe - sv * qo)) |
               ((u32)f2b(0.125f * (sv * qe + cv * qo)) << 16);
    u32 kout = (u32)f2b(cv * ke - sv * ko) | ((u32)f2b(sv * ke + cv * ko) << 16);
    *(u32*)(Qp + addr) = qout;
    *(u32*)(Kp + addr) = kout;
}

// ---------------------------------------------------------------------------
// Causal flash attention, TRANSPOSED scores, NO LDS, NO barriers.
// S^T = K Q^T: C col = lane&15 -> query, row = quad*4+r -> key. Each lane
// owns all scores of ONE query -> softmax reductions are in-lane + 2 shfl.
//
// P^T (C-layout) -> PV A-fragment conversion is a pure cross-quad word
// permutation (col fixed): word w (= key pair 2w,2w+1) moves from
// (src quad = w2w1, slot = w3w0) to (dst quad = w3w2, pos = w1w0).
// Done with a 2-stage shuffle butterfly (xor32 then xor16) = 4 ds_bpermute,
// replacing the previous 8-way-bank-conflicted LDS round trip (~8M conflicts).
//
// Grid (32, bh): one 64-query tile per block, 4 independent waves (16 queries
// each, own causal bound). jt = 31-blockIdx.x dispatches heavy tiles first.
// Defer-max (T13, THR=8) skips the o-rescale on non-growing tiles.
// Qp,Kp: (bh, s, 64)  Vt: (bh, 64, s)  O: (b, s, h*64+d)  bf16
// ---------------------------------------------------------------------------
__global__ __launch_bounds__(256) void flash_attn(const u16* __restrict__ Qp,
                                                  const u16* __restrict__ Kp,
                                                  const u16* __restrict__ Vt,
                                                  u16* __restrict__ O) {
    const int tid  = threadIdx.x;
    const int wave = tid >> 6, lane = tid & 63;
    const int quad = lane >> 4, col = lane & 15;
    const bool hi5 = lane >= 32;
    const bool hi4 = (lane & 16) != 0;
    const int bh = blockIdx.y;
    const int b = bh >> 4, h = bh & 15;
    const int jt = 31 - blockIdx.x;            // heavy tiles first
    const int q0 = jt * 64 + wave * 16;        // this wave's 16 queries

    const u16* Qb = Qp + (size_t)bh * SEQ * 64;
    const u16* Kb = Kp + (size_t)bh * SEQ * 64;
    const u16* Vb = Vt + (size_t)bh * 64 * SEQ;

    // Q as B-operand (n=lane&15 -> query, k=quad*8+j), two K-steps for dk=64
    bf16x8 bq0 = ld_bf8(Qb + (size_t)(q0 + col) * 64 + quad * 8);
    bf16x8 bq1 = ld_bf8(Qb + (size_t)(q0 + col) * 64 + 32 + quad * 8);

    f32x4 zero = {0.f, 0.f, 0.f, 0.f};
    f32x4 o[4] = {zero, zero, zero, zero};
    float m_i = -1e30f, l_i = 0.f;             // per-lane state for query q0+col

    const int qrow = q0 + col;
    const int nkt = (q0 + 47) >> 5;            // tiles needed (keys <= q0+15)
    const int ktm = q0 >> 5;                   // tiles fully below q0: no mask

    for (int kt = 0; kt < nkt; ++kt) {
        const int kb = kt << 5;
        // ---- K as A-operand (m=lane&15 -> key)
        bf16x8 ak00 = ld_bf8(Kb + (size_t)(kb + col) * 64 + quad * 8);
        bf16x8 ak01 = ld_bf8(Kb + (size_t)(kb + col) * 64 + 32 + quad * 8);
        bf16x8 ak10 = ld_bf8(Kb + (size_t)(kb + 16 + col) * 64 + quad * 8);
        bf16x8 ak11 = ld_bf8(Kb + (size_t)(kb + 16 + col) * 64 + 32 + quad * 8);

        // S^T tiles: st[t][r] = score(key = kb + t*16 + quad*4 + r, query)
        f32x4 st0 = zero, st1 = zero;
        st0 = __builtin_amdgcn_mfma_f32_16x16x32_bf16(ak00, bq0, st0, 0, 0, 0);
        st0 = __builtin_amdgcn_mfma_f32_16x16x32_bf16(ak01, bq1, st0, 0, 0, 0);
        st1 = __builtin_amdgcn_mfma_f32_16x16x32_bf16(ak10, bq0, st1, 0, 0, 0);
        st1 = __builtin_amdgcn_mfma_f32_16x16x32_bf16(ak11, bq1, st1, 0, 0, 0);

        float v0[4], v1[4];
        float lm = -1e30f;
        if (kt >= ktm) {                        // wave-uniform: causal edge tile
            for (int r = 0; r < 4; ++r) {
                int key0 = kb + quad * 4 + r;
                float a = (key0 > qrow)      ? -1e30f : st0[r];
                float c = (key0 + 16 > qrow) ? -1e30f : st1[r];
                v0[r] = a; v1[r] = c;
                lm = fmaxf(lm, fmaxf(a, c));
            }
        } else {
            for (int r = 0; r < 4; ++r) {
                v0[r] = st0[r]; v1[r] = st1[r];
                lm = fmaxf(lm, fmaxf(v0[r], v1[r]));
            }
        }
        lm = fmaxf(lm, __shfl_xor(lm, 16));
        lm = fmaxf(lm, __shfl_xor(lm, 32));

        // Defer-max: only pay the rescale when the running max really grows.
        if (!__all(lm - m_i <= 8.f)) {
            float mnew  = fmaxf(m_i, lm);
            float alpha = __expf(m_i - mnew);
            m_i = mnew;
            l_i *= alpha;
            for (int r = 0; r < 4; ++r) {
                float ar = __shfl(alpha, quad * 4 + r);
                for (int nt = 0; nt < 4; ++nt) o[nt][r] *= ar;
            }
        }

        float ls = 0.f;
        for (int r = 0; r < 4; ++r) {
            v0[r] = __expf(v0[r] - m_i);
            v1[r] = __expf(v1[r] - m_i);
            ls += v0[r] + v1[r];
        }
        ls += __shfl_xor(ls, 16);
        ls += __shfl_xor(ls, 32);
        l_i += ls;

        // ---- P^T(C-layout) -> A-fragment via 2-stage shuffle butterfly.
        // Local words: A0=keys(4q,4q+1) A1=(4q+2,4q+3) B0=(16+4q,16+4q+1) B1=+2
        u32 A0 = pk2(v0[0], v0[1]), A1 = pk2(v0[2], v0[3]);
        u32 B0 = pk2(v1[0], v1[1]), B1 = pk2(v1[2], v1[3]);
        // stage 1: exchange slot-bit (A/B) with lane bit 5
        u32 g0 = hi5 ? A0 : B0,  g1 = hi5 ? A1 : B1;
        u32 r0 = __shfl_xor(g0, 32), r1 = __shfl_xor(g1, 32);
        u32 P00 = hi5 ? r0 : A0,  P01 = hi5 ? r1 : A1;   // (s1=0, t0)
        u32 P10 = hi5 ? B0 : r0,  P11 = hi5 ? B1 : r1;   // (s1=1, t0)
        // stage 2: exchange s1 with lane bit 4
        u32 h0 = hi4 ? P00 : P10, h1 = hi4 ? P01 : P11;
        u32 u0 = __shfl_xor(h0, 16), u1 = __shfl_xor(h1, 16);
        u32 fwa[4];
        fwa[0] = hi4 ? u0 : P00;  fwa[1] = hi4 ? u1 : P01;
        fwa[2] = hi4 ? P10 : u0;  fwa[3] = hi4 ? P11 : u1;
        bf16x8 pf;
        __builtin_memcpy(&pf, fwa, 16);

        // ---- PV: o[m=query][n=d] += P[q][k] V[k][d]
        for (int nt = 0; nt < 4; ++nt) {
            bf16x8 bv = ld_bf8(Vb + (size_t)(nt * 16 + col) * SEQ + kb + quad * 8);
            o[nt] = __builtin_amdgcn_mfma_f32_16x16x32_bf16(pf, bv, o[nt], 0, 0, 0);
        }
    }

    float linv = 1.f / l_i;
    for (int r = 0; r < 4; ++r) {
        float lr = __shfl(linv, quad * 4 + r);
        int qr = q0 + quad * 4 + r;
        for (int nt = 0; nt < 4; ++nt)
            O[((size_t)b * SEQ + qr) * DM + h * 64 + nt * 16 + col] =
                f2b(o[nt][r] * lr);
    }
}

// ---------------------------------------------------------------------------
extern "C" void kernel_launch(void* const* d_in, const int* in_sizes, int n_in,
                              void* d_out, int out_size, void* d_ws, size_t ws_size,
                              hipStream_t stream) {
    const float* x    = (const float*)d_in[0];   // fp32 inputs (R3->R5 proven)
    const float* Wq   = (const float*)d_in[2];
    const float* Wk   = (const float*)d_in[3];
    const float* Wv   = (const float*)d_in[4];
    const float* Wo   = (const float*)d_in[5];
    const float* cosT = (const float*)d_in[6];
    const float* sinT = (const float*)d_in[7];
    float* out = (float*)d_out;                  // fp32 output (R8 proven)

    // Workspace: 16,777,216 u16 = 32 MiB (R8-proven safe size).
    u16* ws    = (u16*)d_ws;
    u16* qp    = ws;               // (bh,s,d)
    u16* kp    = ws + 4194304;
    u16* vt    = ws + 8388608;     // (bh,d,s); dead after flash
    u16* woT   = ws + 8388608;     // overlays vt, written after flash
    u16* wqkvT = ws + 12582912;    // dead after gemm_qkv
    u16* ao    = ws + 12582912;    // overlays wqkvT

    dim3 blk(256);
    transpose_wqkv<<<dim3(16, 16, 3), blk, 0, stream>>>(Wq, Wk, Wv, wqkvT);
    gemm_qkv<<<dim3(32, 24), blk, 0, stream>>>(x, wqkvT, qp, kp, vt);
    rope_qk<<<dim3(8192), blk, 0, stream>>>(qp, kp, cosT, sinT);
    flash_attn<<<dim3(32, NBH), blk, 0, stream>>>(qp, kp, vt, ao);
    transpose_wo<<<dim3(16, 16), blk, 0, stream>>>(Wo, woT);
    gemm_wo<<<dim3(32, 8), blk, 0, stream>>>(ao, woT, out);
}

// Round 2
// 334.714 us; speedup vs baseline: 1.1935x; 1.1935x over previous
//
#include <hip/hip_runtime.h>

typedef unsigned short u16;
typedef unsigned int   u32;
typedef __bf16  bf16x8 __attribute__((ext_vector_type(8)));
typedef float   f32x4  __attribute__((ext_vector_type(4)));

#define SEQ    2048
#define HEADS  16
#define DM     1024
#define NBH    32      /* B*H */
#define NBS    4096    /* B*S */

__device__ __forceinline__ u16 f2b(float f) {
    u32 x;
    __builtin_memcpy(&x, &f, 4);
    return (u16)((x + 0x7fffu + ((x >> 16) & 1u)) >> 16);  // RNE
}

__device__ __forceinline__ u32 pk2(float lo, float hi) {
    return (u32)f2b(lo) | ((u32)f2b(hi) << 16);
}

__device__ __forceinline__ bf16x8 ld_bf8(const u16* p) {
    return *(const bf16x8*)p;
}
__device__ __forceinline__ bf16x8 ld_f32x8_cvt(const float* p) {
    f32x4 a = *(const f32x4*)p;
    f32x4 b = *(const f32x4*)(p + 4);
    bf16x8 r;
    r[0] = (__bf16)a[0]; r[1] = (__bf16)a[1]; r[2] = (__bf16)a[2]; r[3] = (__bf16)a[3];
    r[4] = (__bf16)b[0]; r[5] = (__bf16)b[1]; r[6] = (__bf16)b[2]; r[7] = (__bf16)b[3];
    return r;
}

// ---------------------------------------------------------------------------
// Transpose + fp32->bf16 of W_Q/W_K/W_V: (k,n) -> WqkvT[z*1024 + n][k].
// ---------------------------------------------------------------------------
__global__ __launch_bounds__(256) void transpose_wqkv(const float* __restrict__ Wq,
                                                      const float* __restrict__ Wk,
                                                      const float* __restrict__ Wv,
                                                      u16* __restrict__ WqkvT) {
    __shared__ u16 tile[64][65];
    const int z  = blockIdx.z;
    const float* src = (z == 0) ? Wq : (z == 1) ? Wk : Wv;
    const int k0 = blockIdx.x * 64, n0 = blockIdx.y * 64;
    const int tid = threadIdx.x;
    for (int i = 0; i < 16; ++i) {
        int e = i * 256 + tid;
        int r = e >> 6, c = e & 63;
        tile[r][c] = f2b(src[(size_t)(k0 + r) * DM + n0 + c]);
    }
    __syncthreads();
    u16* dst = WqkvT + (size_t)z * DM * DM;
    for (int i = 0; i < 16; ++i) {
        int e = i * 256 + tid;
        int r = e >> 6, c = e & 63;
        dst[(size_t)(n0 + r) * DM + k0 + c] = tile[c][r];
    }
}

// W_O (k,n) fp32 -> WoT[n][k] bf16. Launched AFTER flash (overlays dead vt).
__global__ __launch_bounds__(256) void transpose_wo(const float* __restrict__ Wo,
                                                    u16* __restrict__ WoT) {
    __shared__ u16 tile[64][65];
    const int k0 = blockIdx.x * 64, n0 = blockIdx.y * 64;
    const int tid = threadIdx.x;
    for (int i = 0; i < 16; ++i) {
        int e = i * 256 + tid;
        int r = e >> 6, c = e & 63;
        tile[r][c] = f2b(Wo[(size_t)(k0 + r) * DM + n0 + c]);
    }
    __syncthreads();
    for (int i = 0; i < 16; ++i) {
        int e = i * 256 + tid;
        int r = e >> 6, c = e & 63;
        WoT[(size_t)(n0 + r) * DM + k0 + c] = tile[c][r];
    }
}

// ---------------------------------------------------------------------------
// Shared GEMM body: 128x128 tile, BK=64, VGPR-mediated staging,
// 4 waves 2x2, 4x4 16x16x32 MFMA tiles per wave. acc[][] left for epilogue.
// ---------------------------------------------------------------------------
#define GEMM_BODY(A_EXPR, B_EXPR, K)                                                \
    __shared__ __attribute__((aligned(16))) __bf16 As[128 * 64];                    \
    __shared__ __attribute__((aligned(16))) __bf16 Bs[128 * 64];                    \
    const int tid  = threadIdx.x;                                                   \
    const int wave = tid >> 6, lane = tid & 63;                                     \
    const int quad = lane >> 4, col = lane & 15;                                    \
    const int wm = wave >> 1, wn = wave & 1;                                        \
    const int m0 = blockIdx.x * 128, n0 = blockIdx.y * 128;                         \
    const int srow = tid >> 3;            /* 0..31 */                               \
    const int scol = (tid & 7) * 8;       /* 0..56 */                               \
    f32x4 zero = {0.f, 0.f, 0.f, 0.f};                                              \
    f32x4 acc[4][4];                                                                \
    for (int i = 0; i < 4; ++i)                                                     \
        for (int j = 0; j < 4; ++j) acc[i][j] = zero;                               \
    for (int k0 = 0; k0 < (K); k0 += 64) {                                          \
        bf16x8 av[4], bv[4];                                                        \
        for (int p = 0; p < 4; ++p) {                                               \
            int row = p * 32 + srow;                                                \
            av[p] = A_EXPR;                                                         \
            bv[p] = B_EXPR;                                                         \
        }                                                                           \
        __syncthreads();                                                            \
        for (int p = 0; p < 4; ++p) {                                               \
            int row = p * 32 + srow;                                                \
            *(bf16x8*)&As[row * 64 + scol] = av[p];                                 \
            *(bf16x8*)&Bs[row * 64 + scol] = bv[p];                                 \
        }                                                                           \
        __syncthreads();                                                            \
        for (int ks = 0; ks < 2; ++ks) {                                            \
            bf16x8 af[4], bfr[4];                                                   \
            for (int mt = 0; mt < 4; ++mt)                                          \
                af[mt] = *(const bf16x8*)&As[(wm * 64 + mt * 16 + col) * 64 +       \
                                             ks * 32 + quad * 8];                   \
            for (int nt = 0; nt < 4; ++nt)                                          \
                bfr[nt] = *(const bf16x8*)&Bs[(wn * 64 + nt * 16 + col) * 64 +      \
                                              ks * 32 + quad * 8];                  \
            for (int mt = 0; mt < 4; ++mt)                                          \
                for (int nt = 0; nt < 4; ++nt)                                      \
                    acc[mt][nt] = __builtin_amdgcn_mfma_f32_16x16x32_bf16(          \
                        af[mt], bfr[nt], acc[mt][nt], 0, 0, 0);                     \
        }                                                                           \
    }

// ---------------------------------------------------------------------------
// Fused QKV GEMM: x(4096x1024 fp32) x WqkvT(3072x1024 bf16)^T.
// Epilogue scatters to Qp (bh,s,d), Kp (bh,s,d), Vt (bh,d,s).
// ---------------------------------------------------------------------------
__global__ __launch_bounds__(256) void gemm_qkv(const float* __restrict__ Af,
                                                const u16* __restrict__ Bt,
                                                u16* __restrict__ Qp,
                                                u16* __restrict__ Kp,
                                                u16* __restrict__ Vt) {
    GEMM_BODY(ld_f32x8_cvt(Af + (size_t)(m0 + row) * DM + k0 + scol),
              ld_bf8(Bt + (size_t)(n0 + row) * DM + k0 + scol), DM)
    // C/D: col = lane&15, row = quad*4 + reg (m89-verified).
    for (int mt = 0; mt < 4; ++mt)
        for (int nt = 0; nt < 4; ++nt) {
            int cc = n0 + wn * 64 + nt * 16 + col;       // [0,3072)
            int which = cc >> 10;                        // 0=Q 1=K 2=V
            int c1 = cc & 1023;
            int h = c1 >> 6, d = c1 & 63;
            for (int r = 0; r < 4; ++r) {
                int row = m0 + wm * 64 + mt * 16 + quad * 4 + r;   // [0,4096)
                int b = row >> 11, s = row & (SEQ - 1);
                u16 val = f2b(acc[mt][nt][r]);
                size_t bh = (size_t)(b * HEADS + h);
                if (which == 0)
                    Qp[(bh * SEQ + s) * 64 + d] = val;
                else if (which == 1)
                    Kp[(bh * SEQ + s) * 64 + d] = val;
                else
                    Vt[(bh * 64 + d) * SEQ + s] = val;
            }
        }
}

// ---------------------------------------------------------------------------
// Output GEMM: ao(4096x1024 bf16) x WoT(1024x1024 bf16)^T -> out FP32.
// ---------------------------------------------------------------------------
__global__ __launch_bounds__(256) void gemm_wo(const u16* __restrict__ A,
                                               const u16* __restrict__ Bt,
                                               float* __restrict__ C) {
    GEMM_BODY(ld_bf8(A + (size_t)(m0 + row) * DM + k0 + scol),
              ld_bf8(Bt + (size_t)(n0 + row) * DM + k0 + scol), DM)
    for (int mt = 0; mt < 4; ++mt)
        for (int nt = 0; nt < 4; ++nt)
            for (int r = 0; r < 4; ++r) {
                int row = m0 + wm * 64 + mt * 16 + quad * 4 + r;
                int cc  = n0 + wn * 64 + nt * 16 + col;
                C[(size_t)row * DM + cc] = acc[mt][nt][r];
            }
}

// ---------------------------------------------------------------------------
// RoPE for Q,K in-place on (bh,s,d) bf16; cos/sin fp32 (S x 32).
// token_positions == arange(SEQ). 8192 blocks x 256.
// Folds attention scale 1/sqrt(dk)=0.125 into Q.
// ---------------------------------------------------------------------------
__global__ __launch_bounds__(256) void rope_qk(u16* __restrict__ Qp,
                                               u16* __restrict__ Kp,
                                               const float* __restrict__ cosT,
                                               const float* __restrict__ sinT) {
    int t = blockIdx.x * 256 + threadIdx.x;         // [0, 2^21)
    int p  = t & 31;
    int s  = (t >> 5) & (SEQ - 1);
    int hh = (t >> 16) & (HEADS - 1);
    int b  = t >> 20;

    float cv = cosT[s * 32 + p];
    float sv = sinT[s * 32 + p];

    size_t addr = (((size_t)(b * HEADS + hh)) * SEQ + s) * 64 + 2 * p;
    u32 q2 = *(const u32*)(Qp + addr);
    u32 k2 = *(const u32*)(Kp + addr);
    u32 qe_b = (q2 & 0xffff) << 16, qo_b = q2 & 0xffff0000u;
    u32 ke_b = (k2 & 0xffff) << 16, ko_b = k2 & 0xffff0000u;
    float qe, qo, ke, ko;
    __builtin_memcpy(&qe, &qe_b, 4); __builtin_memcpy(&qo, &qo_b, 4);
    __builtin_memcpy(&ke, &ke_b, 4); __builtin_memcpy(&ko, &ko_b, 4);

    u32 qout = (u32)f2b(0.125f * (cv * qe - sv * qo)) |
               ((u32)f2b(0.125f * (sv * qe + cv * qo)) << 16);
    u32 kout = (u32)f2b(cv * ke - sv * ko) | ((u32)f2b(sv * ke + cv * ko) << 16);
    *(u32*)(Qp + addr) = qout;
    *(u32*)(Kp + addr) = kout;
}

// ---------------------------------------------------------------------------
// Causal flash attention: SPLIT-KEY across the 4 waves of a block.
//
// R1 post-mortem: runtime = (heaviest wave's serial iterations) x (per-iter
// chain latency); TLP cannot shorten one wave's chain. So each block now owns
// ONE 16-query tile and wave w processes key tiles kt = w, w+4, w+8, ...
// with private (m, l, o); a small LDS merge combines the 4 partials.
// Heaviest serial chain: 63 iterations -> 16.
//
// Per-iteration latency cuts:
//  - V loads issued at loop top, next-iteration K prefetched into registers
//    (L2 latency hides under QK+softmax+PV instead of serializing).
//  - l kept as a PER-LANE PARTIAL (linear in the rare rescales), reduced once
//    after the loop: no cross-lane softmax reduce in steady state.
//  - defer-max trigger via __any() on the unreduced in-lane max (same
//    semantics as reduced compare since m_i is quad-uniform): no shuffle.
//  - P^T (C-layout) -> PV A-fragment via the 2-stage shuffle butterfly
//    (R1-verified correct), no LDS round trip.
//
// Grid (128, bh), heavy tiles first. Qp,Kp: (bh,s,64)  Vt: (bh,64,s)
// O: (b, s, h*64+d) bf16.
// ---------------------------------------------------------------------------
__global__ __launch_bounds__(256) void flash_attn(const u16* __restrict__ Qp,
                                                  const u16* __restrict__ Kp,
                                                  const u16* __restrict__ Vt,
                                                  u16* __restrict__ O) {
    __shared__ float os[4][16][68];       // [wave][query][d], +4 pad
    __shared__ float mM[4][16];           // per-wave running max
    __shared__ float mL[4][16];           // per-wave l total
    const int tid  = threadIdx.x;
    const int wave = tid >> 6, lane = tid & 63;
    const int quad = lane >> 4, col = lane & 15;
    const bool hi5 = lane >= 32;
    const bool hi4 = (lane & 16) != 0;
    const int bh = blockIdx.y;
    const int b = bh >> 4, h = bh & 15;
    const int qt = 127 - blockIdx.x;           // heavy tiles first
    const int q0 = qt * 16;                    // block's 16 queries

    const u16* Qb = Qp + (size_t)bh * SEQ * 64;
    const u16* Kb = Kp + (size_t)bh * SEQ * 64;
    const u16* Vb = Vt + (size_t)bh * 64 * SEQ;

    // Q as B-operand (n=lane&15 -> query, k=quad*8+j), two K-steps for dk=64
    bf16x8 bq0 = ld_bf8(Qb + (size_t)(q0 + col) * 64 + quad * 8);
    bf16x8 bq1 = ld_bf8(Qb + (size_t)(q0 + col) * 64 + 32 + quad * 8);

    f32x4 zero = {0.f, 0.f, 0.f, 0.f};
    f32x4 o[4] = {zero, zero, zero, zero};
    float m_i = -1e30f, lp = 0.f;              // lp = PER-LANE partial of l

    const int qrow = q0 + col;
    const int nkt = (q0 + 47) >> 5;            // 32-key tiles covering causal
    const int ktm = q0 >> 5;                   // first tile needing the mask

    int kt = wave;
    bf16x8 ck00, ck01, ck10, ck11;             // current K (prefetched)
    if (kt < nkt) {
        const int kb = kt << 5;
        ck00 = ld_bf8(Kb + (size_t)(kb + col) * 64 + quad * 8);
        ck01 = ld_bf8(Kb + (size_t)(kb + col) * 64 + 32 + quad * 8);
        ck10 = ld_bf8(Kb + (size_t)(kb + 16 + col) * 64 + quad * 8);
        ck11 = ld_bf8(Kb + (size_t)(kb + 16 + col) * 64 + 32 + quad * 8);
    }

    for (; kt < nkt; kt += 4) {
        const int kb = kt << 5;
        // V loads for THIS tile: independent of softmax, in flight until PV.
        bf16x8 bv0 = ld_bf8(Vb + (size_t)(0 * 16 + col) * SEQ + kb + quad * 8);
        bf16x8 bv1 = ld_bf8(Vb + (size_t)(1 * 16 + col) * SEQ + kb + quad * 8);
        bf16x8 bv2 = ld_bf8(Vb + (size_t)(2 * 16 + col) * SEQ + kb + quad * 8);
        bf16x8 bv3 = ld_bf8(Vb + (size_t)(3 * 16 + col) * SEQ + kb + quad * 8);
        // Prefetch NEXT K tile: wait lands after PV, hiding L2 latency.
        const int kn = kt + 4;
        const bool more = kn < nkt;
        bf16x8 nk00, nk01, nk10, nk11;
        if (more) {
            const int kb2 = kn << 5;
            nk00 = ld_bf8(Kb + (size_t)(kb2 + col) * 64 + quad * 8);
            nk01 = ld_bf8(Kb + (size_t)(kb2 + col) * 64 + 32 + quad * 8);
            nk10 = ld_bf8(Kb + (size_t)(kb2 + 16 + col) * 64 + quad * 8);
            nk11 = ld_bf8(Kb + (size_t)(kb2 + 16 + col) * 64 + 32 + quad * 8);
        }

        // S^T tiles: st[t][r] = score(key = kb + t*16 + quad*4 + r, query)
        f32x4 st0 = zero, st1 = zero;
        st0 = __builtin_amdgcn_mfma_f32_16x16x32_bf16(ck00, bq0, st0, 0, 0, 0);
        st0 = __builtin_amdgcn_mfma_f32_16x16x32_bf16(ck01, bq1, st0, 0, 0, 0);
        st1 = __builtin_amdgcn_mfma_f32_16x16x32_bf16(ck10, bq0, st1, 0, 0, 0);
        st1 = __builtin_amdgcn_mfma_f32_16x16x32_bf16(ck11, bq1, st1, 0, 0, 0);

        float v0[4], v1[4];
        float lm = -1e30f;
        if (kt >= ktm) {                        // wave-uniform: causal edge
            for (int r = 0; r < 4; ++r) {
                int key0 = kb + quad * 4 + r;
                float a = (key0 > qrow)      ? -1e30f : st0[r];
                float c = (key0 + 16 > qrow) ? -1e30f : st1[r];
                v0[r] = a; v1[r] = c;
                lm = fmaxf(lm, fmaxf(a, c));
            }
        } else {
            for (int r = 0; r < 4; ++r) {
                v0[r] = st0[r]; v1[r] = st1[r];
                lm = fmaxf(lm, fmaxf(v0[r], v1[r]));
            }
        }

        // Defer-max: no cross-lane reduce unless the max actually grows.
        if (__any(lm > m_i + 8.f)) {
            float lr = fmaxf(lm, __shfl_xor(lm, 16));
            lr = fmaxf(lr, __shfl_xor(lr, 32));
            float mnew  = fmaxf(m_i, lr);
            float alpha = __expf(m_i - mnew);
            m_i = mnew;
            lp *= alpha;                        // per-lane partial scales too
            for (int r = 0; r < 4; ++r) {
                float ar = __shfl(alpha, quad * 4 + r);
                for (int nt = 0; nt < 4; ++nt) o[nt][r] *= ar;
            }
        }

        for (int r = 0; r < 4; ++r) {
            v0[r] = __expf(v0[r] - m_i);
            v1[r] = __expf(v1[r] - m_i);
            lp += v0[r] + v1[r];                // per-lane partial, no shuffle
        }

        // ---- P^T(C-layout) -> A-fragment via 2-stage shuffle butterfly.
        u32 A0 = pk2(v0[0], v0[1]), A1 = pk2(v0[2], v0[3]);
        u32 B0 = pk2(v1[0], v1[1]), B1 = pk2(v1[2], v1[3]);
        u32 g0 = hi5 ? A0 : B0,  g1 = hi5 ? A1 : B1;
        u32 r0 = __shfl_xor(g0, 32), r1 = __shfl_xor(g1, 32);
        u32 P00 = hi5 ? r0 : A0,  P01 = hi5 ? r1 : A1;
        u32 P10 = hi5 ? B0 : r0,  P11 = hi5 ? B1 : r1;
        u32 h0 = hi4 ? P00 : P10, h1 = hi4 ? P01 : P11;
        u32 u0 = __shfl_xor(h0, 16), u1 = __shfl_xor(h1, 16);
        u32 fwa[4];
        fwa[0] = hi4 ? u0 : P00;  fwa[1] = hi4 ? u1 : P01;
        fwa[2] = hi4 ? P10 : u0;  fwa[3] = hi4 ? P11 : u1;
        bf16x8 pf;
        __builtin_memcpy(&pf, fwa, 16);

        // ---- PV: o[m=query][n=d] += P[q][k] V[k][d]
        o[0] = __builtin_amdgcn_mfma_f32_16x16x32_bf16(pf, bv0, o[0], 0, 0, 0);
        o[1] = __builtin_amdgcn_mfma_f32_16x16x32_bf16(pf, bv1, o[1], 0, 0, 0);
        o[2] = __builtin_amdgcn_mfma_f32_16x16x32_bf16(pf, bv2, o[2], 0, 0, 0);
        o[3] = __builtin_amdgcn_mfma_f32_16x16x32_bf16(pf, bv3, o[3], 0, 0, 0);

        if (more) { ck00 = nk00; ck01 = nk01; ck10 = nk10; ck11 = nk11; }
    }

    // ---- wave epilogue: publish partial (m, l, o) to LDS
    float lt = lp;
    lt += __shfl_xor(lt, 16);
    lt += __shfl_xor(lt, 32);                  // total l for query col
    if (quad == 0) {
        mM[wave][col] = m_i;
        mL[wave][col] = lt;
    }
    for (int nt = 0; nt < 4; ++nt)
        for (int r = 0; r < 4; ++r)
            os[wave][quad * 4 + r][nt * 16 + col] = o[nt][r];
    __syncthreads();

    // ---- merge the 4 wave-partials: thread t -> query t>>4, d = (t&15)*4
    {
        const int q  = tid >> 4;
        const int dg = tid & 15;
        float M = mM[0][q];
        M = fmaxf(M, mM[1][q]);
        M = fmaxf(M, mM[2][q]);
        M = fmaxf(M, mM[3][q]);
        float L = 0.f, a0 = 0.f, a1 = 0.f, a2 = 0.f, a3 = 0.f;
        for (int w = 0; w < 4; ++w) {
            float e = __expf(mM[w][q] - M);     // exp(-1e30 - M) = 0 for idle
            L += e * mL[w][q];
            const float* op = &os[w][q][dg * 4];
            a0 += e * op[0]; a1 += e * op[1]; a2 += e * op[2]; a3 += e * op[3];
        }
        float inv = 1.f / L;
        uint2 val;
        val.x = pk2(a0 * inv, a1 * inv);
        val.y = pk2(a2 * inv, a3 * inv);
        *(uint2*)&O[((size_t)b * SEQ + q0 + q) * DM + h * 64 + dg * 4] = val;
    }
}

// ---------------------------------------------------------------------------
extern "C" void kernel_launch(void* const* d_in, const int* in_sizes, int n_in,
                              void* d_out, int out_size, void* d_ws, size_t ws_size,
                              hipStream_t stream) {
    const float* x    = (const float*)d_in[0];   // fp32 inputs (R3->R5 proven)
    const float* Wq   = (const float*)d_in[2];
    const float* Wk   = (const float*)d_in[3];
    const float* Wv   = (const float*)d_in[4];
    const float* Wo   = (const float*)d_in[5];
    const float* cosT = (const float*)d_in[6];
    const float* sinT = (const float*)d_in[7];
    float* out = (float*)d_out;                  // fp32 output (R8 proven)

    // Workspace: 16,777,216 u16 = 32 MiB (R8-proven safe size).
    u16* ws    = (u16*)d_ws;
    u16* qp    = ws;               // (bh,s,d)
    u16* kp    = ws + 4194304;
    u16* vt    = ws + 8388608;     // (bh,d,s); dead after flash
    u16* woT   = ws + 8388608;     // overlays vt, written after flash
    u16* wqkvT = ws + 12582912;    // dead after gemm_qkv
    u16* ao    = ws + 12582912;    // overlays wqkvT

    dim3 blk(256);
    transpose_wqkv<<<dim3(16, 16, 3), blk, 0, stream>>>(Wq, Wk, Wv, wqkvT);
    gemm_qkv<<<dim3(32, 24), blk, 0, stream>>>(x, wqkvT, qp, kp, vt);
    rope_qk<<<dim3(8192), blk, 0, stream>>>(qp, kp, cosT, sinT);
    flash_attn<<<dim3(128, NBH), blk, 0, stream>>>(qp, kp, vt, ao);
    transpose_wo<<<dim3(16, 16), blk, 0, stream>>>(Wo, woT);
    gemm_wo<<<dim3(32, 8), blk, 0, stream>>>(ao, woT, out);
}

// Round 3
// 247.672 us; speedup vs baseline: 1.6130x; 1.3514x over previous
//
#include <hip/hip_runtime.h>

typedef unsigned short u16;
typedef unsigned int   u32;
typedef __bf16  bf16x8 __attribute__((ext_vector_type(8)));
typedef float   f32x4  __attribute__((ext_vector_type(4)));
typedef u32     u32x4  __attribute__((ext_vector_type(4)));

#define SEQ    2048
#define HEADS  16
#define DM     1024
#define NBH    32      /* B*H */
#define NBS    4096    /* B*S */

__device__ __forceinline__ u16 f2b(float f) {
    u32 x;
    __builtin_memcpy(&x, &f, 4);
    return (u16)((x + 0x7fffu + ((x >> 16) & 1u)) >> 16);  // RNE
}

__device__ __forceinline__ u32 pk2(float lo, float hi) {
    return (u32)f2b(lo) | ((u32)f2b(hi) << 16);
}

// Native-cast pack: compiler emits v_cvt_pk_bf16_f32 (RNE on gfx950).
__device__ __forceinline__ u32 pkc(float lo, float hi) {
    __bf16 a = (__bf16)lo, b = (__bf16)hi;
    u16 x, y;
    __builtin_memcpy(&x, &a, 2);
    __builtin_memcpy(&y, &b, 2);
    return (u32)x | ((u32)y << 16);
}

__device__ __forceinline__ bf16x8 ld_bf8(const u16* p) {
    return *(const bf16x8*)p;
}
__device__ __forceinline__ bf16x8 ld_f32x8_cvt(const float* p) {
    f32x4 a = *(const f32x4*)p;
    f32x4 b = *(const f32x4*)(p + 4);
    bf16x8 r;
    r[0] = (__bf16)a[0]; r[1] = (__bf16)a[1]; r[2] = (__bf16)a[2]; r[3] = (__bf16)a[3];
    r[4] = (__bf16)b[0]; r[5] = (__bf16)b[1]; r[6] = (__bf16)b[2]; r[7] = (__bf16)b[3];
    return r;
}

// ---------------------------------------------------------------------------
// Transpose + fp32->bf16 of W_Q/W_K/W_V: (k,n) -> WqkvT[z*1024 + n][k].
// ---------------------------------------------------------------------------
__global__ __launch_bounds__(256) void transpose_wqkv(const float* __restrict__ Wq,
                                                      const float* __restrict__ Wk,
                                                      const float* __restrict__ Wv,
                                                      u16* __restrict__ WqkvT) {
    __shared__ u16 tile[64][65];
    const int z  = blockIdx.z;
    const float* src = (z == 0) ? Wq : (z == 1) ? Wk : Wv;
    const int k0 = blockIdx.x * 64, n0 = blockIdx.y * 64;
    const int tid = threadIdx.x;
    for (int i = 0; i < 16; ++i) {
        int e = i * 256 + tid;
        int r = e >> 6, c = e & 63;
        tile[r][c] = f2b(src[(size_t)(k0 + r) * DM + n0 + c]);
    }
    __syncthreads();
    u16* dst = WqkvT + (size_t)z * DM * DM;
    for (int i = 0; i < 16; ++i) {
        int e = i * 256 + tid;
        int r = e >> 6, c = e & 63;
        dst[(size_t)(n0 + r) * DM + k0 + c] = tile[c][r];
    }
}

// W_O (k,n) fp32 -> WoT[n][k] bf16. Launched AFTER flash (overlays dead vt).
__global__ __launch_bounds__(256) void transpose_wo(const float* __restrict__ Wo,
                                                    u16* __restrict__ WoT) {
    __shared__ u16 tile[64][65];
    const int k0 = blockIdx.x * 64, n0 = blockIdx.y * 64;
    const int tid = threadIdx.x;
    for (int i = 0; i < 16; ++i) {
        int e = i * 256 + tid;
        int r = e >> 6, c = e & 63;
        tile[r][c] = f2b(Wo[(size_t)(k0 + r) * DM + n0 + c]);
    }
    __syncthreads();
    for (int i = 0; i < 16; ++i) {
        int e = i * 256 + tid;
        int r = e >> 6, c = e & 63;
        WoT[(size_t)(n0 + r) * DM + k0 + c] = tile[c][r];
    }
}

// ---------------------------------------------------------------------------
// Shared GEMM body: 128x128 tile, BK=64, VGPR-mediated staging,
// 4 waves 2x2, 4x4 16x16x32 MFMA tiles per wave. acc[][] left for epilogue.
// ---------------------------------------------------------------------------
#define GEMM_BODY(A_EXPR, B_EXPR, K)                                                \
    __shared__ __attribute__((aligned(16))) __bf16 As[128 * 64];                    \
    __shared__ __attribute__((aligned(16))) __bf16 Bs[128 * 64];                    \
    const int tid  = threadIdx.x;                                                   \
    const int wave = tid >> 6, lane = tid & 63;                                     \
    const int quad = lane >> 4, col = lane & 15;                                    \
    const int wm = wave >> 1, wn = wave & 1;                                        \
    const int m0 = blockIdx.x * 128, n0 = blockIdx.y * 128;                         \
    const int srow = tid >> 3;            /* 0..31 */                               \
    const int scol = (tid & 7) * 8;       /* 0..56 */                               \
    f32x4 zero = {0.f, 0.f, 0.f, 0.f};                                              \
    f32x4 acc[4][4];                                                                \
    for (int i = 0; i < 4; ++i)                                                     \
        for (int j = 0; j < 4; ++j) acc[i][j] = zero;                               \
    for (int k0 = 0; k0 < (K); k0 += 64) {                                          \
        bf16x8 av[4], bv[4];                                                        \
        for (int p = 0; p < 4; ++p) {                                               \
            int row = p * 32 + srow;                                                \
            av[p] = A_EXPR;                                                         \
            bv[p] = B_EXPR;                                                         \
        }                                                                           \
        __syncthreads();                                                            \
        for (int p = 0; p < 4; ++p) {                                               \
            int row = p * 32 + srow;                                                \
            *(bf16x8*)&As[row * 64 + scol] = av[p];                                 \
            *(bf16x8*)&Bs[row * 64 + scol] = bv[p];                                 \
        }                                                                           \
        __syncthreads();                                                            \
        for (int ks = 0; ks < 2; ++ks) {                                            \
            bf16x8 af[4], bfr[4];                                                   \
            for (int mt = 0; mt < 4; ++mt)                                          \
                af[mt] = *(const bf16x8*)&As[(wm * 64 + mt * 16 + col) * 64 +       \
                                             ks * 32 + quad * 8];                   \
            for (int nt = 0; nt < 4; ++nt)                                          \
                bfr[nt] = *(const bf16x8*)&Bs[(wn * 64 + nt * 16 + col) * 64 +      \
                                              ks * 32 + quad * 8];                  \
            for (int mt = 0; mt < 4; ++mt)                                          \
                for (int nt = 0; nt < 4; ++nt)                                      \
                    acc[mt][nt] = __builtin_amdgcn_mfma_f32_16x16x32_bf16(          \
                        af[mt], bfr[nt], acc[mt][nt], 0, 0, 0);                     \
        }                                                                           \
    }

// ---------------------------------------------------------------------------
// Fused QKV GEMM: x(4096x1024 fp32) x WqkvT(3072x1024 bf16)^T.
// Epilogue scatters to Qp (bh,s,d), Kp (bh,s,d), Vt (bh,d,s).
// ---------------------------------------------------------------------------
__global__ __launch_bounds__(256) void gemm_qkv(const float* __restrict__ Af,
                                                const u16* __restrict__ Bt,
                                                u16* __restrict__ Qp,
                                                u16* __restrict__ Kp,
                                                u16* __restrict__ Vt) {
    GEMM_BODY(ld_f32x8_cvt(Af + (size_t)(m0 + row) * DM + k0 + scol),
              ld_bf8(Bt + (size_t)(n0 + row) * DM + k0 + scol), DM)
    // C/D: col = lane&15, row = quad*4 + reg (m89-verified).
    for (int mt = 0; mt < 4; ++mt)
        for (int nt = 0; nt < 4; ++nt) {
            int cc = n0 + wn * 64 + nt * 16 + col;       // [0,3072)
            int which = cc >> 10;                        // 0=Q 1=K 2=V
            int c1 = cc & 1023;
            int h = c1 >> 6, d = c1 & 63;
            for (int r = 0; r < 4; ++r) {
                int row = m0 + wm * 64 + mt * 16 + quad * 4 + r;   // [0,4096)
                int b = row >> 11, s = row & (SEQ - 1);
                u16 val = f2b(acc[mt][nt][r]);
                size_t bh = (size_t)(b * HEADS + h);
                if (which == 0)
                    Qp[(bh * SEQ + s) * 64 + d] = val;
                else if (which == 1)
                    Kp[(bh * SEQ + s) * 64 + d] = val;
                else
                    Vt[(bh * 64 + d) * SEQ + s] = val;
            }
        }
}

// ---------------------------------------------------------------------------
// Output GEMM: ao(4096x1024 bf16) x WoT(1024x1024 bf16)^T -> out FP32.
// ---------------------------------------------------------------------------
__global__ __launch_bounds__(256) void gemm_wo(const u16* __restrict__ A,
                                               const u16* __restrict__ Bt,
                                               float* __restrict__ C) {
    GEMM_BODY(ld_bf8(A + (size_t)(m0 + row) * DM + k0 + scol),
              ld_bf8(Bt + (size_t)(n0 + row) * DM + k0 + scol), DM)
    for (int mt = 0; mt < 4; ++mt)
        for (int nt = 0; nt < 4; ++nt)
            for (int r = 0; r < 4; ++r) {
                int row = m0 + wm * 64 + mt * 16 + quad * 4 + r;
                int cc  = n0 + wn * 64 + nt * 16 + col;
                C[(size_t)row * DM + cc] = acc[mt][nt][r];
            }
}

// ---------------------------------------------------------------------------
// RoPE for Q,K in-place on (bh,s,d) bf16; cos/sin fp32 (S x 32).
// token_positions == arange(SEQ). 8192 blocks x 256.
// Folds attention scale 1/sqrt(dk)=0.125 into Q.
// ---------------------------------------------------------------------------
__global__ __launch_bounds__(256) void rope_qk(u16* __restrict__ Qp,
                                               u16* __restrict__ Kp,
                                               const float* __restrict__ cosT,
                                               const float* __restrict__ sinT) {
    int t = blockIdx.x * 256 + threadIdx.x;         // [0, 2^21)
    int p  = t & 31;
    int s  = (t >> 5) & (SEQ - 1);
    int hh = (t >> 16) & (HEADS - 1);
    int b  = t >> 20;

    float cv = cosT[s * 32 + p];
    float sv = sinT[s * 32 + p];

    size_t addr = (((size_t)(b * HEADS + hh)) * SEQ + s) * 64 + 2 * p;
    u32 q2 = *(const u32*)(Qp + addr);
    u32 k2 = *(const u32*)(Kp + addr);
    u32 qe_b = (q2 & 0xffff) << 16, qo_b = q2 & 0xffff0000u;
    u32 ke_b = (k2 & 0xffff) << 16, ko_b = k2 & 0xffff0000u;
    float qe, qo, ke, ko;
    __builtin_memcpy(&qe, &qe_b, 4); __builtin_memcpy(&qo, &qo_b, 4);
    __builtin_memcpy(&ke, &ke_b, 4); __builtin_memcpy(&ko, &ko_b, 4);

    u32 qout = (u32)f2b(0.125f * (cv * qe - sv * qo)) |
               ((u32)f2b(0.125f * (sv * qe + cv * qo)) << 16);
    u32 kout = (u32)f2b(cv * ke - sv * ko) | ((u32)f2b(sv * ke + cv * ko) << 16);
    *(u32*)(Qp + addr) = qout;
    *(u32*)(Kp + addr) = kout;
}

// ---------------------------------------------------------------------------
// Causal flash attention R3: split-key (4 waves) x DUAL 16-query halves.
//
// R2 post-mortem: latency-bound with HBM-class misses (FETCH 3x ideal: every
// XCD touched all 32 bh -> L2 thrash) and single-chain ILP. Fixes:
//  - Block owns 32 queries (two independent softmax chains sharing K/V loads
//    = R0's dual-chain ILP inside the split-key structure).
//  - Grid (bh=32, qt=64): linear wg id % 8 == bh % 8, so round-robin
//    wg->XCD dispatch pins each bh to one XCD; 4 bh/XCD = 2 MB K/V fits L2.
//  - Unconditional clamped K-prefetch: no per-iteration vmcnt(0) drain.
//  - P-pack via native casts (v_cvt_pk_bf16_f32) instead of manual-RNE bit
//    twiddling on the critical chain.
// Qp,Kp: (bh,s,64)  Vt: (bh,64,s)  O: (b, s, h*64+d) bf16.
// ---------------------------------------------------------------------------
__global__ __launch_bounds__(256, 3) void flash_attn(const u16* __restrict__ Qp,
                                                     const u16* __restrict__ Kp,
                                                     const u16* __restrict__ Vt,
                                                     u16* __restrict__ O) {
    __shared__ float os[4][32][68];       // [wave][query][d], +4 pad
    __shared__ float mM[4][32];
    __shared__ float mL[4][32];
    const int tid  = threadIdx.x;
    const int wave = tid >> 6, lane = tid & 63;
    const int quad = lane >> 4, col = lane & 15;
    const bool hi5 = lane >= 32;
    const bool hi4 = (lane & 16) != 0;
    const int bh = blockIdx.x;                 // XCD-pinned: lin%8 == bh%8
    const int b = bh >> 4, h = bh & 15;
    const int qt = 63 - blockIdx.y;            // heavy tiles first
    const int q0 = qt * 32;

    const u16* Qb = Qp + (size_t)bh * SEQ * 64;
    const u16* Kb = Kp + (size_t)bh * SEQ * 64;
    const u16* Vb = Vt + (size_t)bh * 64 * SEQ;

    // Q as B-operand for both halves (n=col -> query, k=quad*8+j)
    bf16x8 bq00 = ld_bf8(Qb + (size_t)(q0 + col) * 64 + quad * 8);
    bf16x8 bq01 = ld_bf8(Qb + (size_t)(q0 + col) * 64 + 32 + quad * 8);
    bf16x8 bq10 = ld_bf8(Qb + (size_t)(q0 + 16 + col) * 64 + quad * 8);
    bf16x8 bq11 = ld_bf8(Qb + (size_t)(q0 + 16 + col) * 64 + 32 + quad * 8);

    f32x4 zero = {0.f, 0.f, 0.f, 0.f};
    f32x4 o0[4] = {zero, zero, zero, zero};
    f32x4 o1[4] = {zero, zero, zero, zero};
    float m0_ = -1e30f, m1_ = -1e30f;
    float lp0 = 0.f, lp1 = 0.f;                // per-lane l partials

    const int nkt = qt + 1;                    // 32-key tiles (causal)
    int kt = wave;
    bf16x8 ck00, ck01, ck10, ck11;
    if (kt < nkt) {
        const int kb = kt << 5;
        ck00 = ld_bf8(Kb + (size_t)(kb + col) * 64 + quad * 8);
        ck01 = ld_bf8(Kb + (size_t)(kb + col) * 64 + 32 + quad * 8);
        ck10 = ld_bf8(Kb + (size_t)(kb + 16 + col) * 64 + quad * 8);
        ck11 = ld_bf8(Kb + (size_t)(kb + 16 + col) * 64 + 32 + quad * 8);
    }

    for (; kt < nkt; kt += 4) {
        const int kb = kt << 5;
        // V for THIS tile (shared by both halves' PV)
        bf16x8 bv0 = ld_bf8(Vb + (size_t)(0 * 16 + col) * SEQ + kb + quad * 8);
        bf16x8 bv1 = ld_bf8(Vb + (size_t)(1 * 16 + col) * SEQ + kb + quad * 8);
        bf16x8 bv2 = ld_bf8(Vb + (size_t)(2 * 16 + col) * SEQ + kb + quad * 8);
        bf16x8 bv3 = ld_bf8(Vb + (size_t)(3 * 16 + col) * SEQ + kb + quad * 8);
        // NEXT K tile, unconditional (clamped: last iter reloads current)
        int kn = kt + 4; if (kn >= nkt) kn = kt;
        const int kb2 = kn << 5;
        bf16x8 nk00 = ld_bf8(Kb + (size_t)(kb2 + col) * 64 + quad * 8);
        bf16x8 nk01 = ld_bf8(Kb + (size_t)(kb2 + col) * 64 + 32 + quad * 8);
        bf16x8 nk10 = ld_bf8(Kb + (size_t)(kb2 + 16 + col) * 64 + quad * 8);
        bf16x8 nk11 = ld_bf8(Kb + (size_t)(kb2 + 16 + col) * 64 + 32 + quad * 8);

        // S^T: two independent chains (halves), 8 MFMA total
        f32x4 s00 = zero, s01 = zero, s10 = zero, s11 = zero;
        s00 = __builtin_amdgcn_mfma_f32_16x16x32_bf16(ck00, bq00, s00, 0, 0, 0);
        s10 = __builtin_amdgcn_mfma_f32_16x16x32_bf16(ck00, bq10, s10, 0, 0, 0);
        s00 = __builtin_amdgcn_mfma_f32_16x16x32_bf16(ck01, bq01, s00, 0, 0, 0);
        s10 = __builtin_amdgcn_mfma_f32_16x16x32_bf16(ck01, bq11, s10, 0, 0, 0);
        s01 = __builtin_amdgcn_mfma_f32_16x16x32_bf16(ck10, bq00, s01, 0, 0, 0);
        s11 = __builtin_amdgcn_mfma_f32_16x16x32_bf16(ck10, bq10, s11, 0, 0, 0);
        s01 = __builtin_amdgcn_mfma_f32_16x16x32_bf16(ck11, bq01, s01, 0, 0, 0);
        s11 = __builtin_amdgcn_mfma_f32_16x16x32_bf16(ck11, bq11, s11, 0, 0, 0);

        float v00[4], v01[4], v10[4], v11[4];
        float lm0 = -1e30f, lm1 = -1e30f;
        if (kt == qt) {                         // diagonal tile (wave-uniform)
            for (int r = 0; r < 4; ++r) {
                int krel = quad * 4 + r;
                // half0: queries q0+col vs keys q0+krel / q0+16+krel
                float a0 = (krel > col) ? -1e30f : s00[r];
                float b0 = -1e30f;              // keys+16 > all half0 queries
                // half1: queries q0+16+col; lo keys always visible
                float a1 = s10[r];
                float b1 = (krel > col) ? -1e30f : s11[r];
                v00[r] = a0; v01[r] = b0; v10[r] = a1; v11[r] = b1;
                lm0 = fmaxf(lm0, fmaxf(a0, b0));
                lm1 = fmaxf(lm1, fmaxf(a1, b1));
            }
        } else {
            for (int r = 0; r < 4; ++r) {
                v00[r] = s00[r]; v01[r] = s01[r];
                v10[r] = s10[r]; v11[r] = s11[r];
                lm0 = fmaxf(lm0, fmaxf(v00[r], v01[r]));
                lm1 = fmaxf(lm1, fmaxf(v10[r], v11[r]));
            }
        }

        // Defer-max: single trigger for both halves
        float dd = fmaxf(lm0 - m0_, lm1 - m1_);
        if (__any(dd > 8.f)) {
            float lr0 = fmaxf(lm0, __shfl_xor(lm0, 16));
            lr0 = fmaxf(lr0, __shfl_xor(lr0, 32));
            float lr1 = fmaxf(lm1, __shfl_xor(lm1, 16));
            lr1 = fmaxf(lr1, __shfl_xor(lr1, 32));
            float mn0 = fmaxf(m0_, lr0), mn1 = fmaxf(m1_, lr1);
            float al0 = __expf(m0_ - mn0), al1 = __expf(m1_ - mn1);
            m0_ = mn0; m1_ = mn1;
            lp0 *= al0; lp1 *= al1;
            for (int r = 0; r < 4; ++r) {
                float ar0 = __shfl(al0, quad * 4 + r);
                float ar1 = __shfl(al1, quad * 4 + r);
                for (int nt = 0; nt < 4; ++nt) {
                    o0[nt][r] *= ar0;
                    o1[nt][r] *= ar1;
                }
            }
        }

        for (int r = 0; r < 4; ++r) {
            v00[r] = __expf(v00[r] - m0_);
            v01[r] = __expf(v01[r] - m0_);
            v10[r] = __expf(v10[r] - m1_);
            v11[r] = __expf(v11[r] - m1_);
            lp0 += v00[r] + v01[r];
            lp1 += v10[r] + v11[r];
        }

        // P^T(C-layout) -> A-fragment: 2-stage shuffle butterfly, per half.
        u32 fwa0[4], fwa1[4];
        {
            u32 A0 = pkc(v00[0], v00[1]), A1 = pkc(v00[2], v00[3]);
            u32 B0 = pkc(v01[0], v01[1]), B1 = pkc(v01[2], v01[3]);
            u32 g0 = hi5 ? A0 : B0,  g1 = hi5 ? A1 : B1;
            u32 r0 = __shfl_xor(g0, 32), r1 = __shfl_xor(g1, 32);
            u32 P00 = hi5 ? r0 : A0,  P01 = hi5 ? r1 : A1;
            u32 P10 = hi5 ? B0 : r0,  P11 = hi5 ? B1 : r1;
            u32 h0 = hi4 ? P00 : P10, h1 = hi4 ? P01 : P11;
            u32 u0 = __shfl_xor(h0, 16), u1 = __shfl_xor(h1, 16);
            fwa0[0] = hi4 ? u0 : P00;  fwa0[1] = hi4 ? u1 : P01;
            fwa0[2] = hi4 ? P10 : u0;  fwa0[3] = hi4 ? P11 : u1;
        }
        {
            u32 A0 = pkc(v10[0], v10[1]), A1 = pkc(v10[2], v10[3]);
            u32 B0 = pkc(v11[0], v11[1]), B1 = pkc(v11[2], v11[3]);
            u32 g0 = hi5 ? A0 : B0,  g1 = hi5 ? A1 : B1;
            u32 r0 = __shfl_xor(g0, 32), r1 = __shfl_xor(g1, 32);
            u32 P00 = hi5 ? r0 : A0,  P01 = hi5 ? r1 : A1;
            u32 P10 = hi5 ? B0 : r0,  P11 = hi5 ? B1 : r1;
            u32 h0 = hi4 ? P00 : P10, h1 = hi4 ? P01 : P11;
            u32 u0 = __shfl_xor(h0, 16), u1 = __shfl_xor(h1, 16);
            fwa1[0] = hi4 ? u0 : P00;  fwa1[1] = hi4 ? u1 : P01;
            fwa1[2] = hi4 ? P10 : u0;  fwa1[3] = hi4 ? P11 : u1;
        }
        bf16x8 pf0, pf1;
        __builtin_memcpy(&pf0, fwa0, 16);
        __builtin_memcpy(&pf1, fwa1, 16);

        // PV: 8 MFMA, independent across halves and nt
        o0[0] = __builtin_amdgcn_mfma_f32_16x16x32_bf16(pf0, bv0, o0[0], 0, 0, 0);
        o1[0] = __builtin_amdgcn_mfma_f32_16x16x32_bf16(pf1, bv0, o1[0], 0, 0, 0);
        o0[1] = __builtin_amdgcn_mfma_f32_16x16x32_bf16(pf0, bv1, o0[1], 0, 0, 0);
        o1[1] = __builtin_amdgcn_mfma_f32_16x16x32_bf16(pf1, bv1, o1[1], 0, 0, 0);
        o0[2] = __builtin_amdgcn_mfma_f32_16x16x32_bf16(pf0, bv2, o0[2], 0, 0, 0);
        o1[2] = __builtin_amdgcn_mfma_f32_16x16x32_bf16(pf1, bv2, o1[2], 0, 0, 0);
        o0[3] = __builtin_amdgcn_mfma_f32_16x16x32_bf16(pf0, bv3, o0[3], 0, 0, 0);
        o1[3] = __builtin_amdgcn_mfma_f32_16x16x32_bf16(pf1, bv3, o1[3], 0, 0, 0);

        ck00 = nk00; ck01 = nk01; ck10 = nk10; ck11 = nk11;
    }

    // ---- publish wave partials
    float lt0 = lp0;
    lt0 += __shfl_xor(lt0, 16); lt0 += __shfl_xor(lt0, 32);
    float lt1 = lp1;
    lt1 += __shfl_xor(lt1, 16); lt1 += __shfl_xor(lt1, 32);
    if (quad == 0) {
        mM[wave][col] = m0_;      mL[wave][col] = lt0;
        mM[wave][16 + col] = m1_; mL[wave][16 + col] = lt1;
    }
    for (int nt = 0; nt < 4; ++nt)
        for (int r = 0; r < 4; ++r) {
            os[wave][quad * 4 + r][nt * 16 + col]      = o0[nt][r];
            os[wave][16 + quad * 4 + r][nt * 16 + col] = o1[nt][r];
        }
    __syncthreads();

    // ---- merge 4 wave-partials: thread t -> query t>>3, d0 = (t&7)*8
    {
        const int q  = tid >> 3;
        const int d0 = (tid & 7) * 8;
        float M = fmaxf(fmaxf(mM[0][q], mM[1][q]), fmaxf(mM[2][q], mM[3][q]));
        float L = 0.f;
        f32x4 a0 = {0.f, 0.f, 0.f, 0.f}, a1 = {0.f, 0.f, 0.f, 0.f};
        for (int w = 0; w < 4; ++w) {
            float e = __expf(mM[w][q] - M);     // 0 for idle waves
            L += e * mL[w][q];
            f32x4 p0 = *(const f32x4*)&os[w][q][d0];
            f32x4 p1 = *(const f32x4*)&os[w][q][d0 + 4];
            for (int j = 0; j < 4; ++j) { a0[j] += e * p0[j]; a1[j] += e * p1[j]; }
        }
        float inv = 1.f / L;
        u32x4 val;
        val[0] = pk2(a0[0] * inv, a0[1] * inv);
        val[1] = pk2(a0[2] * inv, a0[3] * inv);
        val[2] = pk2(a1[0] * inv, a1[1] * inv);
        val[3] = pk2(a1[2] * inv, a1[3] * inv);
        *(u32x4*)&O[((size_t)b * SEQ + q0 + q) * DM + h * 64 + d0] = val;
    }
}

// ---------------------------------------------------------------------------
extern "C" void kernel_launch(void* const* d_in, const int* in_sizes, int n_in,
                              void* d_out, int out_size, void* d_ws, size_t ws_size,
                              hipStream_t stream) {
    const float* x    = (const float*)d_in[0];   // fp32 inputs (R3->R5 proven)
    const float* Wq   = (const float*)d_in[2];
    const float* Wk   = (const float*)d_in[3];
    const float* Wv   = (const float*)d_in[4];
    const float* Wo   = (const float*)d_in[5];
    const float* cosT = (const float*)d_in[6];
    const float* sinT = (const float*)d_in[7];
    float* out = (float*)d_out;                  // fp32 output (R8 proven)

    // Workspace: 16,777,216 u16 = 32 MiB (R8-proven safe size).
    u16* ws    = (u16*)d_ws;
    u16* qp    = ws;               // (bh,s,d)
    u16* kp    = ws + 4194304;
    u16* vt    = ws + 8388608;     // (bh,d,s); dead after flash
    u16* woT   = ws + 8388608;     // overlays vt, written after flash
    u16* wqkvT = ws + 12582912;    // dead after gemm_qkv
    u16* ao    = ws + 12582912;    // overlays wqkvT

    dim3 blk(256);
    transpose_wqkv<<<dim3(16, 16, 3), blk, 0, stream>>>(Wq, Wk, Wv, wqkvT);
    gemm_qkv<<<dim3(32, 24), blk, 0, stream>>>(x, wqkvT, qp, kp, vt);
    rope_qk<<<dim3(8192), blk, 0, stream>>>(qp, kp, cosT, sinT);
    flash_attn<<<dim3(NBH, 64), blk, 0, stream>>>(qp, kp, vt, ao);
    transpose_wo<<<dim3(16, 16), blk, 0, stream>>>(Wo, woT);
    gemm_wo<<<dim3(32, 8), blk, 0, stream>>>(ao, woT, out);
}

// Round 4
// 245.265 us; speedup vs baseline: 1.6288x; 1.0098x over previous
//
#include <hip/hip_runtime.h>

typedef unsigned short u16;
typedef unsigned int   u32;
typedef __bf16  bf16x8 __attribute__((ext_vector_type(8)));
typedef float   f32x4  __attribute__((ext_vector_type(4)));
typedef u32     u32x4  __attribute__((ext_vector_type(4)));

#define SEQ    2048
#define HEADS  16
#define DM     1024
#define NBH    32      /* B*H */
#define NBS    4096    /* B*S */

__device__ __forceinline__ u16 f2b(float f) {
    u32 x;
    __builtin_memcpy(&x, &f, 4);
    return (u16)((x + 0x7fffu + ((x >> 16) & 1u)) >> 16);  // RNE
}

__device__ __forceinline__ u32 pk2(float lo, float hi) {
    return (u32)f2b(lo) | ((u32)f2b(hi) << 16);
}

// Native-cast pack: compiler emits v_cvt_pk_bf16_f32 (RNE on gfx950).
__device__ __forceinline__ u32 pkc(float lo, float hi) {
    __bf16 a = (__bf16)lo, b = (__bf16)hi;
    u16 x, y;
    __builtin_memcpy(&x, &a, 2);
    __builtin_memcpy(&y, &b, 2);
    return (u32)x | ((u32)y << 16);
}

__device__ __forceinline__ bf16x8 ld_bf8(const u16* p) {
    return *(const bf16x8*)p;
}
__device__ __forceinline__ bf16x8 ld_f32x8_cvt(const float* p) {
    f32x4 a = *(const f32x4*)p;
    f32x4 b = *(const f32x4*)(p + 4);
    bf16x8 r;
    r[0] = (__bf16)a[0]; r[1] = (__bf16)a[1]; r[2] = (__bf16)a[2]; r[3] = (__bf16)a[3];
    r[4] = (__bf16)b[0]; r[5] = (__bf16)b[1]; r[6] = (__bf16)b[2]; r[7] = (__bf16)b[3];
    return r;
}

// Async global->LDS, 16 B per lane. LDS dest must be linear (wave-uniform
// base + lane*16); any swizzle goes on the GLOBAL source address (T21).
__device__ __forceinline__ void gl_lds16(const u16* g, __bf16* l) {
    __builtin_amdgcn_global_load_lds(
        (__attribute__((address_space(1))) void*)g,
        (__attribute__((address_space(3))) void*)l,
        16, 0, 0);
}

// ---------------------------------------------------------------------------
// Transpose + fp32->bf16 of W_Q/W_K/W_V: (k,n) -> WqkvT[z*1024 + n][k].
// ---------------------------------------------------------------------------
__global__ __launch_bounds__(256) void transpose_wqkv(const float* __restrict__ Wq,
                                                      const float* __restrict__ Wk,
                                                      const float* __restrict__ Wv,
                                                      u16* __restrict__ WqkvT) {
    __shared__ u16 tile[64][65];
    const int z  = blockIdx.z;
    const float* src = (z == 0) ? Wq : (z == 1) ? Wk : Wv;
    const int k0 = blockIdx.x * 64, n0 = blockIdx.y * 64;
    const int tid = threadIdx.x;
    for (int i = 0; i < 16; ++i) {
        int e = i * 256 + tid;
        int r = e >> 6, c = e & 63;
        tile[r][c] = f2b(src[(size_t)(k0 + r) * DM + n0 + c]);
    }
    __syncthreads();
    u16* dst = WqkvT + (size_t)z * DM * DM;
    for (int i = 0; i < 16; ++i) {
        int e = i * 256 + tid;
        int r = e >> 6, c = e & 63;
        dst[(size_t)(n0 + r) * DM + k0 + c] = tile[c][r];
    }
}

// W_O (k,n) fp32 -> WoT[n][k] bf16. Launched AFTER flash (overlays dead vt).
__global__ __launch_bounds__(256) void transpose_wo(const float* __restrict__ Wo,
                                                    u16* __restrict__ WoT) {
    __shared__ u16 tile[64][65];
    const int k0 = blockIdx.x * 64, n0 = blockIdx.y * 64;
    const int tid = threadIdx.x;
    for (int i = 0; i < 16; ++i) {
        int e = i * 256 + tid;
        int r = e >> 6, c = e & 63;
        tile[r][c] = f2b(Wo[(size_t)(k0 + r) * DM + n0 + c]);
    }
    __syncthreads();
    for (int i = 0; i < 16; ++i) {
        int e = i * 256 + tid;
        int r = e >> 6, c = e & 63;
        WoT[(size_t)(n0 + r) * DM + k0 + c] = tile[c][r];
    }
}

// ---------------------------------------------------------------------------
// GEMM geometry (both GEMMs): 128x128 tile, BK=64, 4 waves 2x2, 4x4 16x16x32
// MFMA per wave. LDS tiles are [row][64 bf16] with 16B chunks XOR-swizzled:
// chunk at slot s of row r holds global chunk s^(r&7) (involution). Fragment
// reads land uniform across banks (8/bank = wave64-b128 minimum).
// ---------------------------------------------------------------------------

// ---------------------------------------------------------------------------
// Fused QKV GEMM: x(4096x1024 fp32) x WqkvT(3072x1024 bf16)^T.
// B staged via global_load_lds (linear dest, swizzled source); A (fp32->bf16)
// reg-staged with swizzled ds_write; A prefetch for k+1 issued after the
// staging barrier so it flies under the 32 MFMAs.
// Epilogue scatters to Qp (bh,s,d), Kp (bh,s,d), Vt (bh,d,s).
// ---------------------------------------------------------------------------
__global__ __launch_bounds__(256) void gemm_qkv(const float* __restrict__ Af,
                                                const u16* __restrict__ Bt,
                                                u16* __restrict__ Qp,
                                                u16* __restrict__ Kp,
                                                u16* __restrict__ Vt) {
    __shared__ __attribute__((aligned(16))) __bf16 As[128 * 64];
    __shared__ __attribute__((aligned(16))) __bf16 Bs[128 * 64];
    const int tid  = threadIdx.x;
    const int wave = tid >> 6, lane = tid & 63;
    const int quad = lane >> 4, col = lane & 15;
    const int wm = wave >> 1, wn = wave & 1;
    const int m0 = blockIdx.x * 128, n0 = blockIdx.y * 128;
    const int srow = tid >> 3;                  // 0..31
    const int sc8  = (tid & 7) * 8;             // source chunk col (elements)
    const int aslot = (((tid & 7) ^ (srow & 7)) << 3);  // swizzled slot (elems)
    const int c7 = col & 7;

    f32x4 zero = {0.f, 0.f, 0.f, 0.f};
    f32x4 acc[4][4];
    for (int i = 0; i < 4; ++i)
        for (int j = 0; j < 4; ++j) acc[i][j] = zero;

    bf16x8 av[4];
#pragma unroll
    for (int p = 0; p < 4; ++p)
        av[p] = ld_f32x8_cvt(Af + (size_t)(m0 + p * 32 + srow) * DM + sc8);

    for (int k0 = 0; k0 < DM; k0 += 64) {
        __syncthreads();                        // prev compute done with LDS
        // B: async global->LDS (linear dest tid*16B; source chunk = slot^(r&7))
#pragma unroll
        for (int p = 0; p < 4; ++p)
            gl_lds16(Bt + (size_t)(n0 + p * 32 + srow) * DM + k0 + aslot,
                     &Bs[p * 2048 + tid * 8]);
        // A: swizzled ds_write of the prefetched registers
#pragma unroll
        for (int p = 0; p < 4; ++p)
            *(bf16x8*)&As[(p * 32 + srow) * 64 + aslot] = av[p];
        __syncthreads();                        // drains gl_lds + ds_write
        // prefetch next A tile: overlaps the MFMAs below
        int kn = k0 + 64; if (kn >= DM) kn = k0;
#pragma unroll
        for (int p = 0; p < 4; ++p)
            av[p] = ld_f32x8_cvt(Af + (size_t)(m0 + p * 32 + srow) * DM + kn + sc8);
#pragma unroll
        for (int ks = 0; ks < 2; ++ks) {
            const int rsl = ((((ks << 2) | quad) ^ c7) << 3);
            bf16x8 af[4], bfr[4];
#pragma unroll
            for (int mt = 0; mt < 4; ++mt)
                af[mt] = *(const bf16x8*)&As[(wm * 64 + mt * 16 + col) * 64 + rsl];
#pragma unroll
            for (int nt = 0; nt < 4; ++nt)
                bfr[nt] = *(const bf16x8*)&Bs[(wn * 64 + nt * 16 + col) * 64 + rsl];
#pragma unroll
            for (int mt = 0; mt < 4; ++mt)
#pragma unroll
                for (int nt = 0; nt < 4; ++nt)
                    acc[mt][nt] = __builtin_amdgcn_mfma_f32_16x16x32_bf16(
                        af[mt], bfr[nt], acc[mt][nt], 0, 0, 0);
        }
    }

    // C/D: col = lane&15, row = quad*4 + reg (m89-verified).
    for (int mt = 0; mt < 4; ++mt)
        for (int nt = 0; nt < 4; ++nt) {
            int cc = n0 + wn * 64 + nt * 16 + col;       // [0,3072)
            int which = cc >> 10;                        // 0=Q 1=K 2=V
            int c1 = cc & 1023;
            int h = c1 >> 6, d = c1 & 63;
            for (int r = 0; r < 4; ++r) {
                int row = m0 + wm * 64 + mt * 16 + quad * 4 + r;   // [0,4096)
                int b = row >> 11, s = row & (SEQ - 1);
                u16 val = f2b(acc[mt][nt][r]);
                size_t bh = (size_t)(b * HEADS + h);
                if (which == 0)
                    Qp[(bh * SEQ + s) * 64 + d] = val;
                else if (which == 1)
                    Kp[(bh * SEQ + s) * 64 + d] = val;
                else
                    Vt[(bh * 64 + d) * SEQ + s] = val;
            }
        }
}

// ---------------------------------------------------------------------------
// Output GEMM: ao(4096x1024 bf16) x WoT(1024x1024 bf16)^T -> out FP32.
// Both operands via global_load_lds (m97 structure + swizzle).
// ---------------------------------------------------------------------------
__global__ __launch_bounds__(256) void gemm_wo(const u16* __restrict__ A,
                                               const u16* __restrict__ Bt,
                                               float* __restrict__ C) {
    __shared__ __attribute__((aligned(16))) __bf16 As[128 * 64];
    __shared__ __attribute__((aligned(16))) __bf16 Bs[128 * 64];
    const int tid  = threadIdx.x;
    const int wave = tid >> 6, lane = tid & 63;
    const int quad = lane >> 4, col = lane & 15;
    const int wm = wave >> 1, wn = wave & 1;
    const int m0 = blockIdx.x * 128, n0 = blockIdx.y * 128;
    const int srow = tid >> 3;
    const int aslot = (((tid & 7) ^ (srow & 7)) << 3);
    const int c7 = col & 7;

    f32x4 zero = {0.f, 0.f, 0.f, 0.f};
    f32x4 acc[4][4];
    for (int i = 0; i < 4; ++i)
        for (int j = 0; j < 4; ++j) acc[i][j] = zero;

    for (int k0 = 0; k0 < DM; k0 += 64) {
        __syncthreads();
#pragma unroll
        for (int p = 0; p < 4; ++p)
            gl_lds16(A + (size_t)(m0 + p * 32 + srow) * DM + k0 + aslot,
                     &As[p * 2048 + tid * 8]);
#pragma unroll
        for (int p = 0; p < 4; ++p)
            gl_lds16(Bt + (size_t)(n0 + p * 32 + srow) * DM + k0 + aslot,
                     &Bs[p * 2048 + tid * 8]);
        __syncthreads();
#pragma unroll
        for (int ks = 0; ks < 2; ++ks) {
            const int rsl = ((((ks << 2) | quad) ^ c7) << 3);
            bf16x8 af[4], bfr[4];
#pragma unroll
            for (int mt = 0; mt < 4; ++mt)
                af[mt] = *(const bf16x8*)&As[(wm * 64 + mt * 16 + col) * 64 + rsl];
#pragma unroll
            for (int nt = 0; nt < 4; ++nt)
                bfr[nt] = *(const bf16x8*)&Bs[(wn * 64 + nt * 16 + col) * 64 + rsl];
#pragma unroll
            for (int mt = 0; mt < 4; ++mt)
#pragma unroll
                for (int nt = 0; nt < 4; ++nt)
                    acc[mt][nt] = __builtin_amdgcn_mfma_f32_16x16x32_bf16(
                        af[mt], bfr[nt], acc[mt][nt], 0, 0, 0);
        }
    }

    for (int mt = 0; mt < 4; ++mt)
        for (int nt = 0; nt < 4; ++nt)
            for (int r = 0; r < 4; ++r) {
                int row = m0 + wm * 64 + mt * 16 + quad * 4 + r;
                int cc  = n0 + wn * 64 + nt * 16 + col;
                C[(size_t)row * DM + cc] = acc[mt][nt][r];
            }
}

// ---------------------------------------------------------------------------
// RoPE for Q,K in-place on (bh,s,d) bf16; cos/sin fp32 (S x 32).
// Vectorized: each thread rotates 4 pairs (dwordx4 per Q/K, f32x4 cos/sin).
// 2048 blocks x 256. Folds attention scale 1/sqrt(dk)=0.125 into Q.
// ---------------------------------------------------------------------------
__global__ __launch_bounds__(256) void rope_qk(u16* __restrict__ Qp,
                                               u16* __restrict__ Kp,
                                               const float* __restrict__ cosT,
                                               const float* __restrict__ sinT) {
    int t = blockIdx.x * 256 + threadIdx.x;         // [0, 2^19)
    int g  = t & 7;                                  // pair-group (4 pairs)
    int s  = (t >> 3) & (SEQ - 1);
    int hh = (t >> 14) & (HEADS - 1);
    int b  = t >> 18;

    f32x4 cv = *(const f32x4*)&cosT[s * 32 + g * 4];
    f32x4 sv = *(const f32x4*)&sinT[s * 32 + g * 4];

    size_t addr = (((size_t)(b * HEADS + hh)) * SEQ + s) * 64 + g * 8;
    u32x4 q4 = *(const u32x4*)(Qp + addr);
    u32x4 k4 = *(const u32x4*)(Kp + addr);
    u32x4 qo4, ko4;
#pragma unroll
    for (int j = 0; j < 4; ++j) {
        u32 q2 = q4[j], k2 = k4[j];
        u32 qe_b = (q2 & 0xffff) << 16, qo_b = q2 & 0xffff0000u;
        u32 ke_b = (k2 & 0xffff) << 16, ko_b = k2 & 0xffff0000u;
        float qe, qo, ke, ko;
        __builtin_memcpy(&qe, &qe_b, 4); __builtin_memcpy(&qo, &qo_b, 4);
        __builtin_memcpy(&ke, &ke_b, 4); __builtin_memcpy(&ko, &ko_b, 4);
        qo4[j] = (u32)f2b(0.125f * (cv[j] * qe - sv[j] * qo)) |
                 ((u32)f2b(0.125f * (sv[j] * qe + cv[j] * qo)) << 16);
        ko4[j] = (u32)f2b(cv[j] * ke - sv[j] * ko) |
                 ((u32)f2b(sv[j] * ke + cv[j] * ko) << 16);
    }
    *(u32x4*)(Qp + addr) = qo4;
    *(u32x4*)(Kp + addr) = ko4;
}

// ---------------------------------------------------------------------------
// Causal flash attention R3 (UNCHANGED — verified): split-key (4 waves) x
// dual 16-query halves, XCD-pinned bh, clamped K-prefetch, shuffle-butterfly
// P-transpose, defer-max, per-lane l partials, LDS merge of wave partials.
// Qp,Kp: (bh,s,64)  Vt: (bh,64,s)  O: (b, s, h*64+d) bf16.
// ---------------------------------------------------------------------------
__global__ __launch_bounds__(256, 3) void flash_attn(const u16* __restrict__ Qp,
                                                     const u16* __restrict__ Kp,
                                                     const u16* __restrict__ Vt,
                                                     u16* __restrict__ O) {
    __shared__ float os[4][32][68];       // [wave][query][d], +4 pad
    __shared__ float mM[4][32];
    __shared__ float mL[4][32];
    const int tid  = threadIdx.x;
    const int wave = tid >> 6, lane = tid & 63;
    const int quad = lane >> 4, col = lane & 15;
    const bool hi5 = lane >= 32;
    const bool hi4 = (lane & 16) != 0;
    const int bh = blockIdx.x;                 // XCD-pinned: lin%8 == bh%8
    const int b = bh >> 4, h = bh & 15;
    const int qt = 63 - blockIdx.y;            // heavy tiles first
    const int q0 = qt * 32;

    const u16* Qb = Qp + (size_t)bh * SEQ * 64;
    const u16* Kb = Kp + (size_t)bh * SEQ * 64;
    const u16* Vb = Vt + (size_t)bh * 64 * SEQ;

    // Q as B-operand for both halves (n=col -> query, k=quad*8+j)
    bf16x8 bq00 = ld_bf8(Qb + (size_t)(q0 + col) * 64 + quad * 8);
    bf16x8 bq01 = ld_bf8(Qb + (size_t)(q0 + col) * 64 + 32 + quad * 8);
    bf16x8 bq10 = ld_bf8(Qb + (size_t)(q0 + 16 + col) * 64 + quad * 8);
    bf16x8 bq11 = ld_bf8(Qb + (size_t)(q0 + 16 + col) * 64 + 32 + quad * 8);

    f32x4 zero = {0.f, 0.f, 0.f, 0.f};
    f32x4 o0[4] = {zero, zero, zero, zero};
    f32x4 o1[4] = {zero, zero, zero, zero};
    float m0_ = -1e30f, m1_ = -1e30f;
    float lp0 = 0.f, lp1 = 0.f;                // per-lane l partials

    const int nkt = qt + 1;                    // 32-key tiles (causal)
    int kt = wave;
    bf16x8 ck00, ck01, ck10, ck11;
    if (kt < nkt) {
        const int kb = kt << 5;
        ck00 = ld_bf8(Kb + (size_t)(kb + col) * 64 + quad * 8);
        ck01 = ld_bf8(Kb + (size_t)(kb + col) * 64 + 32 + quad * 8);
        ck10 = ld_bf8(Kb + (size_t)(kb + 16 + col) * 64 + quad * 8);
        ck11 = ld_bf8(Kb + (size_t)(kb + 16 + col) * 64 + 32 + quad * 8);
    }

    for (; kt < nkt; kt += 4) {
        const int kb = kt << 5;
        // V for THIS tile (shared by both halves' PV)
        bf16x8 bv0 = ld_bf8(Vb + (size_t)(0 * 16 + col) * SEQ + kb + quad * 8);
        bf16x8 bv1 = ld_bf8(Vb + (size_t)(1 * 16 + col) * SEQ + kb + quad * 8);
        bf16x8 bv2 = ld_bf8(Vb + (size_t)(2 * 16 + col) * SEQ + kb + quad * 8);
        bf16x8 bv3 = ld_bf8(Vb + (size_t)(3 * 16 + col) * SEQ + kb + quad * 8);
        // NEXT K tile, unconditional (clamped: last iter reloads current)
        int kn = kt + 4; if (kn >= nkt) kn = kt;
        const int kb2 = kn << 5;
        bf16x8 nk00 = ld_bf8(Kb + (size_t)(kb2 + col) * 64 + quad * 8);
        bf16x8 nk01 = ld_bf8(Kb + (size_t)(kb2 + col) * 64 + 32 + quad * 8);
        bf16x8 nk10 = ld_bf8(Kb + (size_t)(kb2 + 16 + col) * 64 + quad * 8);
        bf16x8 nk11 = ld_bf8(Kb + (size_t)(kb2 + 16 + col) * 64 + 32 + quad * 8);

        // S^T: two independent chains (halves), 8 MFMA total
        f32x4 s00 = zero, s01 = zero, s10 = zero, s11 = zero;
        s00 = __builtin_amdgcn_mfma_f32_16x16x32_bf16(ck00, bq00, s00, 0, 0, 0);
        s10 = __builtin_amdgcn_mfma_f32_16x16x32_bf16(ck00, bq10, s10, 0, 0, 0);
        s00 = __builtin_amdgcn_mfma_f32_16x16x32_bf16(ck01, bq01, s00, 0, 0, 0);
        s10 = __builtin_amdgcn_mfma_f32_16x16x32_bf16(ck01, bq11, s10, 0, 0, 0);
        s01 = __builtin_amdgcn_mfma_f32_16x16x32_bf16(ck10, bq00, s01, 0, 0, 0);
        s11 = __builtin_amdgcn_mfma_f32_16x16x32_bf16(ck10, bq10, s11, 0, 0, 0);
        s01 = __builtin_amdgcn_mfma_f32_16x16x32_bf16(ck11, bq01, s01, 0, 0, 0);
        s11 = __builtin_amdgcn_mfma_f32_16x16x32_bf16(ck11, bq11, s11, 0, 0, 0);

        float v00[4], v01[4], v10[4], v11[4];
        float lm0 = -1e30f, lm1 = -1e30f;
        if (kt == qt) {                         // diagonal tile (wave-uniform)
            for (int r = 0; r < 4; ++r) {
                int krel = quad * 4 + r;
                float a0 = (krel > col) ? -1e30f : s00[r];
                float b0 = -1e30f;              // keys+16 > all half0 queries
                float a1 = s10[r];
                float b1 = (krel > col) ? -1e30f : s11[r];
                v00[r] = a0; v01[r] = b0; v10[r] = a1; v11[r] = b1;
                lm0 = fmaxf(lm0, fmaxf(a0, b0));
                lm1 = fmaxf(lm1, fmaxf(a1, b1));
            }
        } else {
            for (int r = 0; r < 4; ++r) {
                v00[r] = s00[r]; v01[r] = s01[r];
                v10[r] = s10[r]; v11[r] = s11[r];
                lm0 = fmaxf(lm0, fmaxf(v00[r], v01[r]));
                lm1 = fmaxf(lm1, fmaxf(v10[r], v11[r]));
            }
        }

        // Defer-max: single trigger for both halves
        float dd = fmaxf(lm0 - m0_, lm1 - m1_);
        if (__any(dd > 8.f)) {
            float lr0 = fmaxf(lm0, __shfl_xor(lm0, 16));
            lr0 = fmaxf(lr0, __shfl_xor(lr0, 32));
            float lr1 = fmaxf(lm1, __shfl_xor(lm1, 16));
            lr1 = fmaxf(lr1, __shfl_xor(lr1, 32));
            float mn0 = fmaxf(m0_, lr0), mn1 = fmaxf(m1_, lr1);
            float al0 = __expf(m0_ - mn0), al1 = __expf(m1_ - mn1);
            m0_ = mn0; m1_ = mn1;
            lp0 *= al0; lp1 *= al1;
            for (int r = 0; r < 4; ++r) {
                float ar0 = __shfl(al0, quad * 4 + r);
                float ar1 = __shfl(al1, quad * 4 + r);
                for (int nt = 0; nt < 4; ++nt) {
                    o0[nt][r] *= ar0;
                    o1[nt][r] *= ar1;
                }
            }
        }

        for (int r = 0; r < 4; ++r) {
            v00[r] = __expf(v00[r] - m0_);
            v01[r] = __expf(v01[r] - m0_);
            v10[r] = __expf(v10[r] - m1_);
            v11[r] = __expf(v11[r] - m1_);
            lp0 += v00[r] + v01[r];
            lp1 += v10[r] + v11[r];
        }

        // P^T(C-layout) -> A-fragment: 2-stage shuffle butterfly, per half.
        u32 fwa0[4], fwa1[4];
        {
            u32 A0 = pkc(v00[0], v00[1]), A1 = pkc(v00[2], v00[3]);
            u32 B0 = pkc(v01[0], v01[1]), B1 = pkc(v01[2], v01[3]);
            u32 g0 = hi5 ? A0 : B0,  g1 = hi5 ? A1 : B1;
            u32 r0 = __shfl_xor(g0, 32), r1 = __shfl_xor(g1, 32);
            u32 P00 = hi5 ? r0 : A0,  P01 = hi5 ? r1 : A1;
            u32 P10 = hi5 ? B0 : r0,  P11 = hi5 ? B1 : r1;
            u32 h0 = hi4 ? P00 : P10, h1 = hi4 ? P01 : P11;
            u32 u0 = __shfl_xor(h0, 16), u1 = __shfl_xor(h1, 16);
            fwa0[0] = hi4 ? u0 : P00;  fwa0[1] = hi4 ? u1 : P01;
            fwa0[2] = hi4 ? P10 : u0;  fwa0[3] = hi4 ? P11 : u1;
        }
        {
            u32 A0 = pkc(v10[0], v10[1]), A1 = pkc(v10[2], v10[3]);
            u32 B0 = pkc(v11[0], v11[1]), B1 = pkc(v11[2], v11[3]);
            u32 g0 = hi5 ? A0 : B0,  g1 = hi5 ? A1 : B1;
            u32 r0 = __shfl_xor(g0, 32), r1 = __shfl_xor(g1, 32);
            u32 P00 = hi5 ? r0 : A0,  P01 = hi5 ? r1 : A1;
            u32 P10 = hi5 ? B0 : r0,  P11 = hi5 ? B1 : r1;
            u32 h0 = hi4 ? P00 : P10, h1 = hi4 ? P01 : P11;
            u32 u0 = __shfl_xor(h0, 16), u1 = __shfl_xor(h1, 16);
            fwa1[0] = hi4 ? u0 : P00;  fwa1[1] = hi4 ? u1 : P01;
            fwa1[2] = hi4 ? P10 : u0;  fwa1[3] = hi4 ? P11 : u1;
        }
        bf16x8 pf0, pf1;
        __builtin_memcpy(&pf0, fwa0, 16);
        __builtin_memcpy(&pf1, fwa1, 16);

        // PV: 8 MFMA, independent across halves and nt
        o0[0] = __builtin_amdgcn_mfma_f32_16x16x32_bf16(pf0, bv0, o0[0], 0, 0, 0);
        o1[0] = __builtin_amdgcn_mfma_f32_16x16x32_bf16(pf1, bv0, o1[0], 0, 0, 0);
        o0[1] = __builtin_amdgcn_mfma_f32_16x16x32_bf16(pf0, bv1, o0[1], 0, 0, 0);
        o1[1] = __builtin_amdgcn_mfma_f32_16x16x32_bf16(pf1, bv1, o1[1], 0, 0, 0);
        o0[2] = __builtin_amdgcn_mfma_f32_16x16x32_bf16(pf0, bv2, o0[2], 0, 0, 0);
        o1[2] = __builtin_amdgcn_mfma_f32_16x16x32_bf16(pf1, bv2, o1[2], 0, 0, 0);
        o0[3] = __builtin_amdgcn_mfma_f32_16x16x32_bf16(pf0, bv3, o0[3], 0, 0, 0);
        o1[3] = __builtin_amdgcn_mfma_f32_16x16x32_bf16(pf1, bv3, o1[3], 0, 0, 0);

        ck00 = nk00; ck01 = nk01; ck10 = nk10; ck11 = nk11;
    }

    // ---- publish wave partials
    float lt0 = lp0;
    lt0 += __shfl_xor(lt0, 16); lt0 += __shfl_xor(lt0, 32);
    float lt1 = lp1;
    lt1 += __shfl_xor(lt1, 16); lt1 += __shfl_xor(lt1, 32);
    if (quad == 0) {
        mM[wave][col] = m0_;      mL[wave][col] = lt0;
        mM[wave][16 + col] = m1_; mL[wave][16 + col] = lt1;
    }
    for (int nt = 0; nt < 4; ++nt)
        for (int r = 0; r < 4; ++r) {
            os[wave][quad * 4 + r][nt * 16 + col]      = o0[nt][r];
            os[wave][16 + quad * 4 + r][nt * 16 + col] = o1[nt][r];
        }
    __syncthreads();

    // ---- merge 4 wave-partials: thread t -> query t>>3, d0 = (t&7)*8
    {
        const int q  = tid >> 3;
        const int d0 = (tid & 7) * 8;
        float M = fmaxf(fmaxf(mM[0][q], mM[1][q]), fmaxf(mM[2][q], mM[3][q]));
        float L = 0.f;
        f32x4 a0 = {0.f, 0.f, 0.f, 0.f}, a1 = {0.f, 0.f, 0.f, 0.f};
        for (int w = 0; w < 4; ++w) {
            float e = __expf(mM[w][q] - M);     // 0 for idle waves
            L += e * mL[w][q];
            f32x4 p0 = *(const f32x4*)&os[w][q][d0];
            f32x4 p1 = *(const f32x4*)&os[w][q][d0 + 4];
            for (int j = 0; j < 4; ++j) { a0[j] += e * p0[j]; a1[j] += e * p1[j]; }
        }
        float inv = 1.f / L;
        u32x4 val;
        val[0] = pk2(a0[0] * inv, a0[1] * inv);
        val[1] = pk2(a0[2] * inv, a0[3] * inv);
        val[2] = pk2(a1[0] * inv, a1[1] * inv);
        val[3] = pk2(a1[2] * inv, a1[3] * inv);
        *(u32x4*)&O[((size_t)b * SEQ + q0 + q) * DM + h * 64 + d0] = val;
    }
}

// ---------------------------------------------------------------------------
extern "C" void kernel_launch(void* const* d_in, const int* in_sizes, int n_in,
                              void* d_out, int out_size, void* d_ws, size_t ws_size,
                              hipStream_t stream) {
    const float* x    = (const float*)d_in[0];   // fp32 inputs (R3->R5 proven)
    const float* Wq   = (const float*)d_in[2];
    const float* Wk   = (const float*)d_in[3];
    const float* Wv   = (const float*)d_in[4];
    const float* Wo   = (const float*)d_in[5];
    const float* cosT = (const float*)d_in[6];
    const float* sinT = (const float*)d_in[7];
    float* out = (float*)d_out;                  // fp32 output (R8 proven)

    // Workspace: 16,777,216 u16 = 32 MiB (R8-proven safe size).
    u16* ws    = (u16*)d_ws;
    u16* qp    = ws;               // (bh,s,d)
    u16* kp    = ws + 4194304;
    u16* vt    = ws + 8388608;     // (bh,d,s); dead after flash
    u16* woT   = ws + 8388608;     // overlays vt, written after flash
    u16* wqkvT = ws + 12582912;    // dead after gemm_qkv
    u16* ao    = ws + 12582912;    // overlays wqkvT

    dim3 blk(256);
    transpose_wqkv<<<dim3(16, 16, 3), blk, 0, stream>>>(Wq, Wk, Wv, wqkvT);
    gemm_qkv<<<dim3(32, 24), blk, 0, stream>>>(x, wqkvT, qp, kp, vt);
    rope_qk<<<dim3(2048), blk, 0, stream>>>(qp, kp, cosT, sinT);
    flash_attn<<<dim3(NBH, 64), blk, 0, stream>>>(qp, kp, vt, ao);
    transpose_wo<<<dim3(16, 16), blk, 0, stream>>>(Wo, woT);
    gemm_wo<<<dim3(32, 8), blk, 0, stream>>>(ao, woT, out);
}

// Round 5
// 233.499 us; speedup vs baseline: 1.7109x; 1.0504x over previous
//
#include <hip/hip_runtime.h>

typedef unsigned short u16;
typedef unsigned int   u32;
typedef __bf16  bf16x8 __attribute__((ext_vector_type(8)));
typedef float   f32x4  __attribute__((ext_vector_type(4)));
typedef u32     u32x4  __attribute__((ext_vector_type(4)));

#define SEQ    2048
#define HEADS  16
#define DM     1024
#define NBH    32      /* B*H */
#define NBS    4096    /* B*S */

// log2(e): flash softmax runs in exp2 domain; folded into Q's RoPE scale.
#define LOG2E  1.4426950408889634f

__device__ __forceinline__ u16 f2b(float f) {
    u32 x;
    __builtin_memcpy(&x, &f, 4);
    return (u16)((x + 0x7fffu + ((x >> 16) & 1u)) >> 16);  // RNE
}

// Native-cast pack: compiler emits v_cvt_pk_bf16_f32 (RNE on gfx950).
__device__ __forceinline__ u32 pkc(float lo, float hi) {
    __bf16 a = (__bf16)lo, b = (__bf16)hi;
    u16 x, y;
    __builtin_memcpy(&x, &a, 2);
    __builtin_memcpy(&y, &b, 2);
    return (u32)x | ((u32)y << 16);
}

__device__ __forceinline__ bf16x8 ld_bf8(const u16* p) {
    return *(const bf16x8*)p;
}

// Async global->LDS, 16 B per lane. LDS dest must be linear (wave-uniform
// base + lane*16); any swizzle goes on the GLOBAL source address (T21).
__device__ __forceinline__ void gl_lds16(const u16* g, __bf16* l) {
    __builtin_amdgcn_global_load_lds(
        (__attribute__((address_space(1))) void*)g,
        (__attribute__((address_space(3))) void*)l,
        16, 0, 0);
}

// ---------------------------------------------------------------------------
// Transpose + fp32->bf16 of W_Q/W_K/W_V: (k,n) -> WqkvT[z*1024 + n][k].
// ---------------------------------------------------------------------------
__global__ __launch_bounds__(256) void transpose_wqkv(const float* __restrict__ Wq,
                                                      const float* __restrict__ Wk,
                                                      const float* __restrict__ Wv,
                                                      u16* __restrict__ WqkvT) {
    __shared__ u16 tile[64][65];
    const int z  = blockIdx.z;
    const float* src = (z == 0) ? Wq : (z == 1) ? Wk : Wv;
    const int k0 = blockIdx.x * 64, n0 = blockIdx.y * 64;
    const int tid = threadIdx.x;
    for (int i = 0; i < 16; ++i) {
        int e = i * 256 + tid;
        int r = e >> 6, c = e & 63;
        tile[r][c] = f2b(src[(size_t)(k0 + r) * DM + n0 + c]);
    }
    __syncthreads();
    u16* dst = WqkvT + (size_t)z * DM * DM;
    for (int i = 0; i < 16; ++i) {
        int e = i * 256 + tid;
        int r = e >> 6, c = e & 63;
        dst[(size_t)(n0 + r) * DM + k0 + c] = tile[c][r];
    }
}

// W_O (k,n) fp32 -> WoT[n][k] bf16. Launched AFTER flash (overlays dead vt).
__global__ __launch_bounds__(256) void transpose_wo(const float* __restrict__ Wo,
                                                    u16* __restrict__ WoT) {
    __shared__ u16 tile[64][65];
    const int k0 = blockIdx.x * 64, n0 = blockIdx.y * 64;
    const int tid = threadIdx.x;
    for (int i = 0; i < 16; ++i) {
        int e = i * 256 + tid;
        int r = e >> 6, c = e & 63;
        tile[r][c] = f2b(Wo[(size_t)(k0 + r) * DM + n0 + c]);
    }
    __syncthreads();
    for (int i = 0; i < 16; ++i) {
        int e = i * 256 + tid;
        int r = e >> 6, c = e & 63;
        WoT[(size_t)(n0 + r) * DM + k0 + c] = tile[c][r];
    }
}

// ---------------------------------------------------------------------------
// x fp32 -> bf16, 8 elems/thread. Output xb lives in the (dead until gemm_wo)
// fp32 output buffer: gemm_wo rewrites every byte of `out` afterwards.
// ---------------------------------------------------------------------------
__global__ __launch_bounds__(256) void cvt_x(const float* __restrict__ x,
                                             u16* __restrict__ xb) {
    int t = blockIdx.x * 256 + threadIdx.x;     // [0, 524288)
    const float* p = x + (size_t)t * 8;
    f32x4 a = *(const f32x4*)p;
    f32x4 b = *(const f32x4*)(p + 4);
    u32x4 v;
    v[0] = pkc(a[0], a[1]);
    v[1] = pkc(a[2], a[3]);
    v[2] = pkc(b[0], b[1]);
    v[3] = pkc(b[2], b[3]);
    *(u32x4*)(xb + (size_t)t * 8) = v;
}

// ---------------------------------------------------------------------------
// Fused QKV GEMM: xb(4096x1024 bf16) x WqkvT(3072x1024 bf16)^T.
// 128x128 tile, BK=64, both operands via global_load_lds (linear dest,
// inverse-swizzled source; XOR-swizzled fragment reads). Zero staging VALU.
// Epilogue scatters to Qp (bh,s,d), Kp (bh,s,d), Vt (bh,d,s).
// ---------------------------------------------------------------------------
__global__ __launch_bounds__(256) void gemm_qkv(const u16* __restrict__ Ab,
                                                const u16* __restrict__ Bt,
                                                u16* __restrict__ Qp,
                                                u16* __restrict__ Kp,
                                                u16* __restrict__ Vt) {
    __shared__ __attribute__((aligned(16))) __bf16 As[128 * 64];
    __shared__ __attribute__((aligned(16))) __bf16 Bs[128 * 64];
    const int tid  = threadIdx.x;
    const int wave = tid >> 6, lane = tid & 63;
    const int quad = lane >> 4, col = lane & 15;
    const int wm = wave >> 1, wn = wave & 1;
    const int m0 = blockIdx.x * 128, n0 = blockIdx.y * 128;
    const int srow = tid >> 3;                  // 0..31
    const int aslot = (((tid & 7) ^ (srow & 7)) << 3);  // swizzled slot (elems)
    const int c7 = col & 7;

    f32x4 zero = {0.f, 0.f, 0.f, 0.f};
    f32x4 acc[4][4];
    for (int i = 0; i < 4; ++i)
        for (int j = 0; j < 4; ++j) acc[i][j] = zero;

    for (int k0 = 0; k0 < DM; k0 += 64) {
        __syncthreads();
#pragma unroll
        for (int p = 0; p < 4; ++p)
            gl_lds16(Ab + (size_t)(m0 + p * 32 + srow) * DM + k0 + aslot,
                     &As[p * 2048 + tid * 8]);
#pragma unroll
        for (int p = 0; p < 4; ++p)
            gl_lds16(Bt + (size_t)(n0 + p * 32 + srow) * DM + k0 + aslot,
                     &Bs[p * 2048 + tid * 8]);
        __syncthreads();
#pragma unroll
        for (int ks = 0; ks < 2; ++ks) {
            const int rsl = ((((ks << 2) | quad) ^ c7) << 3);
            bf16x8 af[4], bfr[4];
#pragma unroll
            for (int mt = 0; mt < 4; ++mt)
                af[mt] = *(const bf16x8*)&As[(wm * 64 + mt * 16 + col) * 64 + rsl];
#pragma unroll
            for (int nt = 0; nt < 4; ++nt)
                bfr[nt] = *(const bf16x8*)&Bs[(wn * 64 + nt * 16 + col) * 64 + rsl];
#pragma unroll
            for (int mt = 0; mt < 4; ++mt)
#pragma unroll
                for (int nt = 0; nt < 4; ++nt)
                    acc[mt][nt] = __builtin_amdgcn_mfma_f32_16x16x32_bf16(
                        af[mt], bfr[nt], acc[mt][nt], 0, 0, 0);
        }
    }

    // C/D: col = lane&15, row = quad*4 + reg (m89-verified).
    for (int mt = 0; mt < 4; ++mt)
        for (int nt = 0; nt < 4; ++nt) {
            int cc = n0 + wn * 64 + nt * 16 + col;       // [0,3072)
            int which = cc >> 10;                        // 0=Q 1=K 2=V
            int c1 = cc & 1023;
            int h = c1 >> 6, d = c1 & 63;
            for (int r = 0; r < 4; ++r) {
                int row = m0 + wm * 64 + mt * 16 + quad * 4 + r;   // [0,4096)
                int b = row >> 11, s = row & (SEQ - 1);
                u16 val = f2b(acc[mt][nt][r]);
                size_t bh = (size_t)(b * HEADS + h);
                if (which == 0)
                    Qp[(bh * SEQ + s) * 64 + d] = val;
                else if (which == 1)
                    Kp[(bh * SEQ + s) * 64 + d] = val;
                else
                    Vt[(bh * 64 + d) * SEQ + s] = val;
            }
        }
}

// ---------------------------------------------------------------------------
// Output GEMM: ao(4096x1024 bf16) x WoT(1024x1024 bf16)^T -> out FP32.
// 128x64 tile -> grid (32,16) = 512 blocks = 2 blocks/CU (R4 had 256 = 1/CU:
// barrier drains had zero co-resident cover). 4 waves stacked on M (wm=wave).
// ---------------------------------------------------------------------------
__global__ __launch_bounds__(256) void gemm_wo(const u16* __restrict__ A,
                                               const u16* __restrict__ Bt,
                                               float* __restrict__ C) {
    __shared__ __attribute__((aligned(16))) __bf16 As[128 * 64];
    __shared__ __attribute__((aligned(16))) __bf16 Bs[64 * 64];
    const int tid  = threadIdx.x;
    const int wave = tid >> 6, lane = tid & 63;
    const int quad = lane >> 4, col = lane & 15;
    const int m0 = blockIdx.x * 128, n0 = blockIdx.y * 64;
    const int srow = tid >> 3;
    const int aslot = (((tid & 7) ^ (srow & 7)) << 3);
    const int c7 = col & 7;

    f32x4 zero = {0.f, 0.f, 0.f, 0.f};
    f32x4 acc[2][4];
    for (int i = 0; i < 2; ++i)
        for (int j = 0; j < 4; ++j) acc[i][j] = zero;

    for (int k0 = 0; k0 < DM; k0 += 64) {
        __syncthreads();
#pragma unroll
        for (int p = 0; p < 4; ++p)
            gl_lds16(A + (size_t)(m0 + p * 32 + srow) * DM + k0 + aslot,
                     &As[p * 2048 + tid * 8]);
#pragma unroll
        for (int p = 0; p < 2; ++p)
            gl_lds16(Bt + (size_t)(n0 + p * 32 + srow) * DM + k0 + aslot,
                     &Bs[p * 2048 + tid * 8]);
        __syncthreads();
#pragma unroll
        for (int ks = 0; ks < 2; ++ks) {
            const int rsl = ((((ks << 2) | quad) ^ c7) << 3);
            bf16x8 af[2], bfr[4];
#pragma unroll
            for (int mt = 0; mt < 2; ++mt)
                af[mt] = *(const bf16x8*)&As[(wave * 32 + mt * 16 + col) * 64 + rsl];
#pragma unroll
            for (int nt = 0; nt < 4; ++nt)
                bfr[nt] = *(const bf16x8*)&Bs[(nt * 16 + col) * 64 + rsl];
#pragma unroll
            for (int mt = 0; mt < 2; ++mt)
#pragma unroll
                for (int nt = 0; nt < 4; ++nt)
                    acc[mt][nt] = __builtin_amdgcn_mfma_f32_16x16x32_bf16(
                        af[mt], bfr[nt], acc[mt][nt], 0, 0, 0);
        }
    }

    for (int mt = 0; mt < 2; ++mt)
        for (int nt = 0; nt < 4; ++nt)
            for (int r = 0; r < 4; ++r) {
                int row = m0 + wave * 32 + mt * 16 + quad * 4 + r;
                int cc  = n0 + nt * 16 + col;
                C[(size_t)row * DM + cc] = acc[mt][nt][r];
            }
}

// ---------------------------------------------------------------------------
// RoPE for Q,K in-place on (bh,s,d) bf16; cos/sin fp32 (S x 32).
// Vectorized 4 pairs/thread. Q gets 0.125*log2(e): flash's softmax runs in
// exp2 domain (scores pre-scaled so v_exp_f32 applies directly, no mul).
// ---------------------------------------------------------------------------
__global__ __launch_bounds__(256) void rope_qk(u16* __restrict__ Qp,
                                               u16* __restrict__ Kp,
                                               const float* __restrict__ cosT,
                                               const float* __restrict__ sinT) {
    int t = blockIdx.x * 256 + threadIdx.x;         // [0, 2^19)
    int g  = t & 7;                                  // pair-group (4 pairs)
    int s  = (t >> 3) & (SEQ - 1);
    int hh = (t >> 14) & (HEADS - 1);
    int b  = t >> 18;

    f32x4 cv = *(const f32x4*)&cosT[s * 32 + g * 4];
    f32x4 sv = *(const f32x4*)&sinT[s * 32 + g * 4];

    const float QS = 0.125f * LOG2E;
    size_t addr = (((size_t)(b * HEADS + hh)) * SEQ + s) * 64 + g * 8;
    u32x4 q4 = *(const u32x4*)(Qp + addr);
    u32x4 k4 = *(const u32x4*)(Kp + addr);
    u32x4 qo4, ko4;
#pragma unroll
    for (int j = 0; j < 4; ++j) {
        u32 q2 = q4[j], k2 = k4[j];
        u32 qe_b = (q2 & 0xffff) << 16, qo_b = q2 & 0xffff0000u;
        u32 ke_b = (k2 & 0xffff) << 16, ko_b = k2 & 0xffff0000u;
        float qe, qo, ke, ko;
        __builtin_memcpy(&qe, &qe_b, 4); __builtin_memcpy(&qo, &qo_b, 4);
        __builtin_memcpy(&ke, &ke_b, 4); __builtin_memcpy(&ko, &ko_b, 4);
        qo4[j] = (u32)f2b(QS * (cv[j] * qe - sv[j] * qo)) |
                 ((u32)f2b(QS * (sv[j] * qe + cv[j] * qo)) << 16);
        ko4[j] = (u32)f2b(cv[j] * ke - sv[j] * ko) |
                 ((u32)f2b(sv[j] * ke + cv[j] * ko) << 16);
    }
    *(u32x4*)(Qp + addr) = qo4;
    *(u32x4*)(Kp + addr) = ko4;
}

// ---------------------------------------------------------------------------
// Causal flash attention: split-key (4 waves) x dual 16-query halves,
// XCD-pinned bh, K AND V prefetched one full iteration ahead, exp2-domain
// softmax (scale folded into Q), shuffle-butterfly P-transpose, defer-max
// (threshold 8*log2e = 11.54), per-lane l partials, LDS merge.
// Qp,Kp: (bh,s,64)  Vt: (bh,64,s)  O: (b, s, h*64+d) bf16.
// ---------------------------------------------------------------------------
__global__ __launch_bounds__(256, 3) void flash_attn(const u16* __restrict__ Qp,
                                                     const u16* __restrict__ Kp,
                                                     const u16* __restrict__ Vt,
                                                     u16* __restrict__ O) {
    __shared__ float os[4][32][68];       // [wave][query][d], +4 pad
    __shared__ float mM[4][32];
    __shared__ float mL[4][32];
    const int tid  = threadIdx.x;
    const int wave = tid >> 6, lane = tid & 63;
    const int quad = lane >> 4, col = lane & 15;
    const bool hi5 = lane >= 32;
    const bool hi4 = (lane & 16) != 0;
    const int bh = blockIdx.x;                 // XCD-pinned: lin%8 == bh%8
    const int b = bh >> 4, h = bh & 15;
    const int qt = 63 - blockIdx.y;            // heavy tiles first
    const int q0 = qt * 32;

    const u16* Qb = Qp + (size_t)bh * SEQ * 64;
    const u16* Kb = Kp + (size_t)bh * SEQ * 64;
    const u16* Vb = Vt + (size_t)bh * 64 * SEQ;

    // Q as B-operand for both halves (n=col -> query, k=quad*8+j)
    bf16x8 bq00 = ld_bf8(Qb + (size_t)(q0 + col) * 64 + quad * 8);
    bf16x8 bq01 = ld_bf8(Qb + (size_t)(q0 + col) * 64 + 32 + quad * 8);
    bf16x8 bq10 = ld_bf8(Qb + (size_t)(q0 + 16 + col) * 64 + quad * 8);
    bf16x8 bq11 = ld_bf8(Qb + (size_t)(q0 + 16 + col) * 64 + 32 + quad * 8);

    f32x4 zero = {0.f, 0.f, 0.f, 0.f};
    f32x4 o0[4] = {zero, zero, zero, zero};
    f32x4 o1[4] = {zero, zero, zero, zero};
    float m0_ = -1e30f, m1_ = -1e30f;
    float lp0 = 0.f, lp1 = 0.f;                // per-lane l partials

    const int nkt = qt + 1;                    // 32-key tiles (causal)
    int kt = wave;
    bf16x8 ck00, ck01, ck10, ck11, cv0, cv1, cv2, cv3;
    if (kt < nkt) {
        const int kb = kt << 5;
        ck00 = ld_bf8(Kb + (size_t)(kb + col) * 64 + quad * 8);
        ck01 = ld_bf8(Kb + (size_t)(kb + col) * 64 + 32 + quad * 8);
        ck10 = ld_bf8(Kb + (size_t)(kb + 16 + col) * 64 + quad * 8);
        ck11 = ld_bf8(Kb + (size_t)(kb + 16 + col) * 64 + 32 + quad * 8);
        cv0  = ld_bf8(Vb + (size_t)(0 * 16 + col) * SEQ + kb + quad * 8);
        cv1  = ld_bf8(Vb + (size_t)(1 * 16 + col) * SEQ + kb + quad * 8);
        cv2  = ld_bf8(Vb + (size_t)(2 * 16 + col) * SEQ + kb + quad * 8);
        cv3  = ld_bf8(Vb + (size_t)(3 * 16 + col) * SEQ + kb + quad * 8);
    }

    for (; kt < nkt; kt += 4) {
        const int kb = kt << 5;
        // NEXT K and V tiles, unconditional (clamped on last iteration)
        int kn = kt + 4; if (kn >= nkt) kn = kt;
        const int kb2 = kn << 5;
        bf16x8 nk00 = ld_bf8(Kb + (size_t)(kb2 + col) * 64 + quad * 8);
        bf16x8 nk01 = ld_bf8(Kb + (size_t)(kb2 + col) * 64 + 32 + quad * 8);
        bf16x8 nk10 = ld_bf8(Kb + (size_t)(kb2 + 16 + col) * 64 + quad * 8);
        bf16x8 nk11 = ld_bf8(Kb + (size_t)(kb2 + 16 + col) * 64 + 32 + quad * 8);
        bf16x8 nv0  = ld_bf8(Vb + (size_t)(0 * 16 + col) * SEQ + kb2 + quad * 8);
        bf16x8 nv1  = ld_bf8(Vb + (size_t)(1 * 16 + col) * SEQ + kb2 + quad * 8);
        bf16x8 nv2  = ld_bf8(Vb + (size_t)(2 * 16 + col) * SEQ + kb2 + quad * 8);
        bf16x8 nv3  = ld_bf8(Vb + (size_t)(3 * 16 + col) * SEQ + kb2 + quad * 8);

        // S^T (log2-domain): two independent chains, 8 MFMA
        f32x4 s00 = zero, s01 = zero, s10 = zero, s11 = zero;
        s00 = __builtin_amdgcn_mfma_f32_16x16x32_bf16(ck00, bq00, s00, 0, 0, 0);
        s10 = __builtin_amdgcn_mfma_f32_16x16x32_bf16(ck00, bq10, s10, 0, 0, 0);
        s00 = __builtin_amdgcn_mfma_f32_16x16x32_bf16(ck01, bq01, s00, 0, 0, 0);
        s10 = __builtin_amdgcn_mfma_f32_16x16x32_bf16(ck01, bq11, s10, 0, 0, 0);
        s01 = __builtin_amdgcn_mfma_f32_16x16x32_bf16(ck10, bq00, s01, 0, 0, 0);
        s11 = __builtin_amdgcn_mfma_f32_16x16x32_bf16(ck10, bq10, s11, 0, 0, 0);
        s01 = __builtin_amdgcn_mfma_f32_16x16x32_bf16(ck11, bq01, s01, 0, 0, 0);
        s11 = __builtin_amdgcn_mfma_f32_16x16x32_bf16(ck11, bq11, s11, 0, 0, 0);

        float v00[4], v01[4], v10[4], v11[4];
        float lm0 = -1e30f, lm1 = -1e30f;
        if (kt == qt) {                         // diagonal tile (wave-uniform)
            for (int r = 0; r < 4; ++r) {
                int krel = quad * 4 + r;
                float a0 = (krel > col) ? -1e30f : s00[r];
                float b0 = -1e30f;              // keys+16 > all half0 queries
                float a1 = s10[r];
                float b1 = (krel > col) ? -1e30f : s11[r];
                v00[r] = a0; v01[r] = b0; v10[r] = a1; v11[r] = b1;
                lm0 = fmaxf(lm0, fmaxf(a0, b0));
                lm1 = fmaxf(lm1, fmaxf(a1, b1));
            }
        } else {
            for (int r = 0; r < 4; ++r) {
                v00[r] = s00[r]; v01[r] = s01[r];
                v10[r] = s10[r]; v11[r] = s11[r];
                lm0 = fmaxf(lm0, fmaxf(v00[r], v01[r]));
                lm1 = fmaxf(lm1, fmaxf(v10[r], v11[r]));
            }
        }

        // Defer-max (log2 domain: 8*log2e = 11.54)
        float dd = fmaxf(lm0 - m0_, lm1 - m1_);
        if (__any(dd > 11.54f)) {
            float lr0 = fmaxf(lm0, __shfl_xor(lm0, 16));
            lr0 = fmaxf(lr0, __shfl_xor(lr0, 32));
            float lr1 = fmaxf(lm1, __shfl_xor(lm1, 16));
            lr1 = fmaxf(lr1, __shfl_xor(lr1, 32));
            float mn0 = fmaxf(m0_, lr0), mn1 = fmaxf(m1_, lr1);
            float al0 = __builtin_amdgcn_exp2f(m0_ - mn0);
            float al1 = __builtin_amdgcn_exp2f(m1_ - mn1);
            m0_ = mn0; m1_ = mn1;
            lp0 *= al0; lp1 *= al1;
            for (int r = 0; r < 4; ++r) {
                float ar0 = __shfl(al0, quad * 4 + r);
                float ar1 = __shfl(al1, quad * 4 + r);
                for (int nt = 0; nt < 4; ++nt) {
                    o0[nt][r] *= ar0;
                    o1[nt][r] *= ar1;
                }
            }
        }

        for (int r = 0; r < 4; ++r) {
            v00[r] = __builtin_amdgcn_exp2f(v00[r] - m0_);
            v01[r] = __builtin_amdgcn_exp2f(v01[r] - m0_);
            v10[r] = __builtin_amdgcn_exp2f(v10[r] - m1_);
            v11[r] = __builtin_amdgcn_exp2f(v11[r] - m1_);
            lp0 += v00[r] + v01[r];
            lp1 += v10[r] + v11[r];
        }

        // P^T(C-layout) -> A-fragment: 2-stage shuffle butterfly, per half.
        u32 fwa0[4], fwa1[4];
        {
            u32 A0 = pkc(v00[0], v00[1]), A1 = pkc(v00[2], v00[3]);
            u32 B0 = pkc(v01[0], v01[1]), B1 = pkc(v01[2], v01[3]);
            u32 g0 = hi5 ? A0 : B0,  g1 = hi5 ? A1 : B1;
            u32 r0 = __shfl_xor(g0, 32), r1 = __shfl_xor(g1, 32);
            u32 P00 = hi5 ? r0 : A0,  P01 = hi5 ? r1 : A1;
            u32 P10 = hi5 ? B0 : r0,  P11 = hi5 ? B1 : r1;
            u32 h0 = hi4 ? P00 : P10, h1 = hi4 ? P01 : P11;
            u32 u0 = __shfl_xor(h0, 16), u1 = __shfl_xor(h1, 16);
            fwa0[0] = hi4 ? u0 : P00;  fwa0[1] = hi4 ? u1 : P01;
            fwa0[2] = hi4 ? P10 : u0;  fwa0[3] = hi4 ? P11 : u1;
        }
        {
            u32 A0 = pkc(v10[0], v10[1]), A1 = pkc(v10[2], v10[3]);
            u32 B0 = pkc(v11[0], v11[1]), B1 = pkc(v11[2], v11[3]);
            u32 g0 = hi5 ? A0 : B0,  g1 = hi5 ? A1 : B1;
            u32 r0 = __shfl_xor(g0, 32), r1 = __shfl_xor(g1, 32);
            u32 P00 = hi5 ? r0 : A0,  P01 = hi5 ? r1 : A1;
            u32 P10 = hi5 ? B0 : r0,  P11 = hi5 ? B1 : r1;
            u32 h0 = hi4 ? P00 : P10, h1 = hi4 ? P01 : P11;
            u32 u0 = __shfl_xor(h0, 16), u1 = __shfl_xor(h1, 16);
            fwa1[0] = hi4 ? u0 : P00;  fwa1[1] = hi4 ? u1 : P01;
            fwa1[2] = hi4 ? P10 : u0;  fwa1[3] = hi4 ? P11 : u1;
        }
        bf16x8 pf0, pf1;
        __builtin_memcpy(&pf0, fwa0, 16);
        __builtin_memcpy(&pf1, fwa1, 16);

        // PV: 8 MFMA, independent across halves and nt
        o0[0] = __builtin_amdgcn_mfma_f32_16x16x32_bf16(pf0, cv0, o0[0], 0, 0, 0);
        o1[0] = __builtin_amdgcn_mfma_f32_16x16x32_bf16(pf1, cv0, o1[0], 0, 0, 0);
        o0[1] = __builtin_amdgcn_mfma_f32_16x16x32_bf16(pf0, cv1, o0[1], 0, 0, 0);
        o1[1] = __builtin_amdgcn_mfma_f32_16x16x32_bf16(pf1, cv1, o1[1], 0, 0, 0);
        o0[2] = __builtin_amdgcn_mfma_f32_16x16x32_bf16(pf0, cv2, o0[2], 0, 0, 0);
        o1[2] = __builtin_amdgcn_mfma_f32_16x16x32_bf16(pf1, cv2, o1[2], 0, 0, 0);
        o0[3] = __builtin_amdgcn_mfma_f32_16x16x32_bf16(pf0, cv3, o0[3], 0, 0, 0);
        o1[3] = __builtin_amdgcn_mfma_f32_16x16x32_bf16(pf1, cv3, o1[3], 0, 0, 0);

        ck00 = nk00; ck01 = nk01; ck10 = nk10; ck11 = nk11;
        cv0 = nv0; cv1 = nv1; cv2 = nv2; cv3 = nv3;
    }

    // ---- publish wave partials
    float lt0 = lp0;
    lt0 += __shfl_xor(lt0, 16); lt0 += __shfl_xor(lt0, 32);
    float lt1 = lp1;
    lt1 += __shfl_xor(lt1, 16); lt1 += __shfl_xor(lt1, 32);
    if (quad == 0) {
        mM[wave][col] = m0_;      mL[wave][col] = lt0;
        mM[wave][16 + col] = m1_; mL[wave][16 + col] = lt1;
    }
    for (int nt = 0; nt < 4; ++nt)
        for (int r = 0; r < 4; ++r) {
            os[wave][quad * 4 + r][nt * 16 + col]      = o0[nt][r];
            os[wave][16 + quad * 4 + r][nt * 16 + col] = o1[nt][r];
        }
    __syncthreads();

    // ---- merge 4 wave-partials: thread t -> query t>>3, d0 = (t&7)*8
    {
        const int q  = tid >> 3;
        const int d0 = (tid & 7) * 8;
        float M = fmaxf(fmaxf(mM[0][q], mM[1][q]), fmaxf(mM[2][q], mM[3][q]));
        float L = 0.f;
        f32x4 a0 = {0.f, 0.f, 0.f, 0.f}, a1 = {0.f, 0.f, 0.f, 0.f};
        for (int w = 0; w < 4; ++w) {
            float e = __builtin_amdgcn_exp2f(mM[w][q] - M);  // 0 for idle waves
            L += e * mL[w][q];
            f32x4 p0 = *(const f32x4*)&os[w][q][d0];
            f32x4 p1 = *(const f32x4*)&os[w][q][d0 + 4];
            for (int j = 0; j < 4; ++j) { a0[j] += e * p0[j]; a1[j] += e * p1[j]; }
        }
        float inv = 1.f / L;
        u32x4 val;
        val[0] = pkc(a0[0] * inv, a0[1] * inv);
        val[1] = pkc(a0[2] * inv, a0[3] * inv);
        val[2] = pkc(a1[0] * inv, a1[1] * inv);
        val[3] = pkc(a1[2] * inv, a1[3] * inv);
        *(u32x4*)&O[((size_t)b * SEQ + q0 + q) * DM + h * 64 + d0] = val;
    }
}

// ---------------------------------------------------------------------------
extern "C" void kernel_launch(void* const* d_in, const int* in_sizes, int n_in,
                              void* d_out, int out_size, void* d_ws, size_t ws_size,
                              hipStream_t stream) {
    const float* x    = (const float*)d_in[0];   // fp32 inputs (R3->R5 proven)
    const float* Wq   = (const float*)d_in[2];
    const float* Wk   = (const float*)d_in[3];
    const float* Wv   = (const float*)d_in[4];
    const float* Wo   = (const float*)d_in[5];
    const float* cosT = (const float*)d_in[6];
    const float* sinT = (const float*)d_in[7];
    float* out = (float*)d_out;                  // fp32 output (R8 proven)

    // Workspace: 16,777,216 u16 = 32 MiB (R8-proven safe size).
    u16* ws    = (u16*)d_ws;
    u16* qp    = ws;               // (bh,s,d)
    u16* kp    = ws + 4194304;
    u16* vt    = ws + 8388608;     // (bh,d,s); dead after flash
    u16* woT   = ws + 8388608;     // overlays vt, written after flash
    u16* wqkvT = ws + 12582912;    // dead after gemm_qkv
    u16* ao    = ws + 12582912;    // overlays wqkvT
    // bf16 copy of x lives in the OUTPUT buffer (8 of its 16 MiB): out is
    // dead until gemm_wo, which rewrites every element afterwards.
    u16* xb    = (u16*)out;

    dim3 blk(256);
    transpose_wqkv<<<dim3(16, 16, 3), blk, 0, stream>>>(Wq, Wk, Wv, wqkvT);
    cvt_x<<<dim3(2048), blk, 0, stream>>>(x, xb);
    gemm_qkv<<<dim3(32, 24), blk, 0, stream>>>(xb, wqkvT, qp, kp, vt);
    rope_qk<<<dim3(2048), blk, 0, stream>>>(qp, kp, cosT, sinT);
    flash_attn<<<dim3(NBH, 64), blk, 0, stream>>>(qp, kp, vt, ao);
    transpose_wo<<<dim3(16, 16), blk, 0, stream>>>(Wo, woT);
    gemm_wo<<<dim3(32, 16), blk, 0, stream>>>(ao, woT, out);
}